// Round 10
// baseline (7195.784 us; speedup 1.0000x reference)
//
#include <hip/hip_runtime.h>

#define NNODE 50000
#define NEDGE 800000
#define NLAYER 4
#define BN_EPS 1e-5f

#define NH (NNODE*64)   // 3,200,000
#define NE (NEDGE*64)   // 51,200,000

typedef __attribute__((ext_vector_type(8))) short short8v;
typedef unsigned short us;

__device__ __forceinline__ float sigf(float x){ return 1.0f/(1.0f+__expf(-x)); }

// bf16 helpers (e state)
__device__ __forceinline__ float bf2f(us u){
  union { unsigned int i; float f; } c; c.i = ((unsigned int)u)<<16; return c.f;
}
__device__ __forceinline__ us f2bf(float f){
  union { float f; unsigned int i; } c; c.f = f;
  unsigned int r = c.i + 0x7FFFu + ((c.i>>16)&1u);   // RNE
  return (us)(r>>16);
}
// fp16 helpers (t, Vh, Bh, Ch)
__device__ __forceinline__ float hf2f(us u){
  union { us u; _Float16 h; } c; c.u=u; return (float)c.h;
}
__device__ __forceinline__ us f2hf(float f){
  union { us u; _Float16 h; } c; c.h=(_Float16)f; return c.u;
}

// ---------------------------------------------------------------- utility
__global__ void k_zero_i(int* __restrict__ p, int n){
  int i = blockIdx.x*256 + threadIdx.x;
  if(i<n) p[i]=0;
}
__global__ void k_zero_stats(float* __restrict__ stats){
  stats[threadIdx.x] = 0.f;   // one block of 256
}
__global__ void k_count(const int* __restrict__ ei, int* __restrict__ cnt){
  int i = blockIdx.x*256 + threadIdx.x;
  if(i<NEDGE) atomicAdd(&cnt[ei[i]], 1);   // ei[0][i] = dst
}
__global__ void k_inv(const int* __restrict__ cnt, float* __restrict__ invc){
  int i = blockIdx.x*256 + threadIdx.x;
  if(i<NNODE){ int c=cnt[i]; invc[i] = 1.0f/(float)(c<1?1:c); }
}

// single-block exclusive scan of cnt -> row_ptr (+cursor copy)
__global__ void k_scan(const int* __restrict__ cnt, int* __restrict__ row_ptr,
                       int* __restrict__ cursor){
  __shared__ int buf[256];
  __shared__ int carry;
  const int tid = threadIdx.x;
  if(tid==0) carry=0;
  __syncthreads();
  for(int base=0; base<NNODE; base+=256){
    int i = base+tid;
    int v = (i<NNODE)? cnt[i] : 0;
    buf[tid]=v; __syncthreads();
    #pragma unroll
    for(int off=1; off<256; off<<=1){
      int t = (tid>=off)? buf[tid-off] : 0;
      __syncthreads();
      buf[tid]+=t;
      __syncthreads();
    }
    int excl = carry + buf[tid]-v;
    if(i<NNODE){ row_ptr[i]=excl; cursor[i]=excl; }
    __syncthreads();
    if(tid==0) carry += buf[255];
    __syncthreads();
  }
  if(tid==0) row_ptr[NNODE]=carry;
}

__global__ void k_fill(const int* __restrict__ ei, int* __restrict__ cursor,
                       int* __restrict__ eidP){
  int i = blockIdx.x*256 + threadIdx.x;
  if(i<NEDGE){
    int pos = atomicAdd(&cursor[ei[i]], 1);
    eidP[pos] = i;
  }
}

__global__ void k_perm(const int* __restrict__ ei, const int* __restrict__ eidP,
                       int* __restrict__ dstP, int* __restrict__ srcP){
  int p = blockIdx.x*256 + threadIdx.x;
  if(p<NEDGE){
    int eid = eidP[p];
    dstP[p] = ei[eid];
    srcP[p] = ei[NEDGE+eid];
  }
}

__global__ void k_init_h(const float* __restrict__ x, const float* __restrict__ w,
                         const float* __restrict__ b, float* __restrict__ h){
  int t = blockIdx.x*256 + threadIdx.x;
  if(t>=NH) return;
  int i=t>>6, j=t&63;
  float v = x[2*i]*w[j] + x[2*i+1]*w[64+j] + b[j];
  h[t] = fmaxf(v, 0.0f);
}

__global__ void k_init_e(const float* __restrict__ ea, const int* __restrict__ eidP,
                         const float* __restrict__ w, const float* __restrict__ b,
                         us* __restrict__ e){
  int t = blockIdx.x*256 + threadIdx.x;      // pair index
  if(t >= NE/2) return;
  int p = t>>5;          // slot
  int j = (t&31)<<1;
  float a = ea[eidP[p]];
  float v0 = fmaxf(a*w[j]   + b[j],   0.f);
  float v1 = fmaxf(a*w[j+1] + b[j+1], 0.f);
  unsigned int pk = (unsigned int)f2bf(v0) | ((unsigned int)f2bf(v1)<<16);
  *reinterpret_cast<unsigned int*>(&e[2*t]) = pk;
}

// ------------------------------------------------------------ tile helpers
__device__ __forceinline__ void tile_gemm(const float (&At)[64][68], const float (&Ws)[64][68],
                                          int r0, int c0, float (&acc)[4][4]){
  #pragma unroll 4
  for(int k=0;k<64;++k){
    const float4 a = *reinterpret_cast<const float4*>(&At[k][r0]);
    const float4 b = *reinterpret_cast<const float4*>(&Ws[k][c0]);
    const float av[4]={a.x,a.y,a.z,a.w};
    const float bv[4]={b.x,b.y,b.z,b.w};
    #pragma unroll
    for(int ri=0;ri<4;++ri)
      #pragma unroll
      for(int ci=0;ci<4;++ci)
        acc[ri][ci] = fmaf(av[ri], bv[ci], acc[ri][ci]);
  }
}

// GEMM with bf16 LDS A-tile (converted on read)
__device__ __forceinline__ void tile_gemm_bf(const us (&Ats)[64][68], const float (&Ws)[64][68],
                                             int r0, int c0, float (&acc)[4][4]){
  #pragma unroll 4
  for(int k=0;k<64;++k){
    const ushort4 a = *reinterpret_cast<const ushort4*>(&Ats[k][r0]);
    const float4 b = *reinterpret_cast<const float4*>(&Ws[k][c0]);
    const float av[4]={bf2f(a.x),bf2f(a.y),bf2f(a.z),bf2f(a.w)};
    const float bv[4]={b.x,b.y,b.z,b.w};
    #pragma unroll
    for(int ri=0;ri<4;++ri)
      #pragma unroll
      for(int ci=0;ci<4;++ci)
        acc[ri][ci] = fmaf(av[ri], bv[ci], acc[ri][ci]);
  }
}

__device__ __forceinline__ void stage_At_f32(float (&At)[64][68], const float* __restrict__ src,
                                             int row0, int rowmax, int tid){
  for(int it=0; it<4; ++it){
    int idx = tid + it*256;
    int r = idx>>4, c4=(idx&15)<<2;
    int gr = row0 + r;
    float4 v = make_float4(0.f,0.f,0.f,0.f);
    if(gr < rowmax) v = *reinterpret_cast<const float4*>(&src[(size_t)gr*64 + c4]);
    At[c4+0][r]=v.x; At[c4+1][r]=v.y; At[c4+2][r]=v.z; At[c4+3][r]=v.w;
  }
}

// f32 LDS tile from bf16 source (k_mlp)
__device__ __forceinline__ void stage_At_bf16(float (&At)[64][68], const us* __restrict__ src,
                                              int row0, int tid){
  #pragma unroll
  for(int it=0; it<2; ++it){
    int idx = tid + it*256;          // 0..511
    int r = idx>>3, c8 = (idx&7)<<3;
    int gr = row0 + r;
    const short8v v = *reinterpret_cast<const short8v*>(&src[(size_t)gr*64 + c8]);
    #pragma unroll
    for(int j=0;j<8;++j) At[c8+j][r] = bf2f((us)v[j]);
  }
}

// raw-bf16 LDS tile (k_edge_A)
__device__ __forceinline__ void stage_Ats_raw(us (&Ats)[64][68], const us* __restrict__ src,
                                              int row0, int tid){
  #pragma unroll
  for(int it=0; it<2; ++it){
    int idx = tid + it*256;          // 0..511
    int r = idx>>3, c8 = (idx&7)<<3;
    int gr = row0 + r;
    const short8v v = *reinterpret_cast<const short8v*>(&src[(size_t)gr*64 + c8]);
    #pragma unroll
    for(int j=0;j<8;++j) Ats[c8+j][r] = (us)v[j];
  }
}

__device__ __forceinline__ void stage_W(float (&Ws)[64][68], const float* __restrict__ W, int tid){
  for(int it=0; it<4; ++it){
    int idx = tid + it*256;
    int k = idx>>4, c4=(idx&15)<<2;
    *reinterpret_cast<float4*>(&Ws[k][c4]) = *reinterpret_cast<const float4*>(&W[k*64+c4]);
  }
}

// ---------------------------------------------------------- node GEMMs
__device__ __forceinline__ void node_one_mat_f32(float (&At)[64][68], float (&Ws)[64][68],
    const float* __restrict__ W, const float* __restrict__ B, float* __restrict__ O,
    int row0, int tid){
  __syncthreads();
  stage_W(Ws, W, tid);
  __syncthreads();
  const int tx=tid&15, ty=tid>>4, r0=tx<<2, c0=ty<<2;
  float acc[4][4]={{0.f}};
  tile_gemm(At, Ws, r0, c0, acc);
  const float4 b4 = *reinterpret_cast<const float4*>(&B[c0]);
  const float bb[4]={b4.x,b4.y,b4.z,b4.w};
  #pragma unroll
  for(int ri=0;ri<4;++ri){
    int gr = row0 + r0 + ri;
    if(gr < NNODE){
      float4 o = make_float4(acc[ri][0]+bb[0], acc[ri][1]+bb[1],
                             acc[ri][2]+bb[2], acc[ri][3]+bb[3]);
      *reinterpret_cast<float4*>(&O[(size_t)gr*64 + c0]) = o;
    }
  }
}

__device__ __forceinline__ void node_one_mat_f16(float (&At)[64][68], float (&Ws)[64][68],
    const float* __restrict__ W, const float* __restrict__ B, us* __restrict__ O,
    int row0, int tid){
  __syncthreads();
  stage_W(Ws, W, tid);
  __syncthreads();
  const int tx=tid&15, ty=tid>>4, r0=tx<<2, c0=ty<<2;
  float acc[4][4]={{0.f}};
  tile_gemm(At, Ws, r0, c0, acc);
  const float4 b4 = *reinterpret_cast<const float4*>(&B[c0]);
  const float bb[4]={b4.x,b4.y,b4.z,b4.w};
  #pragma unroll
  for(int ri=0;ri<4;++ri){
    int gr = row0 + r0 + ri;
    if(gr < NNODE){
      unsigned int p0 = (unsigned int)f2hf(acc[ri][0]+bb[0]) | ((unsigned int)f2hf(acc[ri][1]+bb[1])<<16);
      unsigned int p1 = (unsigned int)f2hf(acc[ri][2]+bb[2]) | ((unsigned int)f2hf(acc[ri][3]+bb[3])<<16);
      *reinterpret_cast<uint2*>(&O[(size_t)gr*64 + c0]) = make_uint2(p0,p1);
    }
  }
}

__global__ __launch_bounds__(256) void k_node_gemm(
    const float* __restrict__ h,
    const float* __restrict__ Uw, const float* __restrict__ Ub,
    const float* __restrict__ Vw, const float* __restrict__ Vb,
    const float* __restrict__ Bw, const float* __restrict__ Bb,
    const float* __restrict__ Cw, const float* __restrict__ Cb,
    float* __restrict__ Uh, us* __restrict__ Vh,
    us* __restrict__ Bh, us* __restrict__ Ch)
{
  __shared__ float At[64][68];
  __shared__ float Ws[64][68];
  const int tid = threadIdx.x;
  const int row0 = blockIdx.x*64;
  stage_At_f32(At, h, row0, NNODE, tid);
  node_one_mat_f32(At, Ws, Uw, Ub, Uh, row0, tid);
  node_one_mat_f16(At, Ws, Vw, Vb, Vh, row0, tid);
  node_one_mat_f16(At, Ws, Bw, Bb, Bh, row0, tid);
  node_one_mat_f16(At, Ws, Cw, Cb, Ch, row0, tid);
}

// ---------------------------------------------------------- edge pass A
// t = e@Aw + Ab + Bh[dstP] + Ch[srcP]; store t (f16); e-BN stats via shfl.
// bf16 LDS tile (26.1 KB total) -> 6 blocks/CU; gathers issued before GEMM.
__global__ __launch_bounds__(256, 6) void k_edge_A(
    const us* __restrict__ e,
    const float* __restrict__ Aw, const float* __restrict__ Ab,
    const us* __restrict__ Bh, const us* __restrict__ Ch,
    const int* __restrict__ dstP, const int* __restrict__ srcP,
    us* __restrict__ t16, float* __restrict__ stats)
{
  __shared__ us Ats[64][68];     // 8704 B
  __shared__ float Ws[64][68];   // 17408 B
  const int tid=threadIdx.x;
  const int row0 = blockIdx.x*64;
  stage_Ats_raw(Ats, e, row0, tid);
  stage_W(Ws, Aw, tid);

  const int tx=tid&15, ty=tid>>4, r0=tx<<2, c0=ty<<2;
  // index loads before the barrier (independent of LDS)
  int dstI[4], srcI[4];
  #pragma unroll
  for(int ri=0;ri<4;++ri){
    dstI[ri]=dstP[row0+r0+ri];
    srcI[ri]=srcP[row0+r0+ri];
  }
  __syncthreads();
  // issue gathers NOW; they fly under the GEMM
  uint2 bh2[4], ch2[4];
  #pragma unroll
  for(int ri=0;ri<4;++ri){
    bh2[ri] = *reinterpret_cast<const uint2*>(&Bh[(size_t)dstI[ri]*64 + c0]);
    ch2[ri] = *reinterpret_cast<const uint2*>(&Ch[(size_t)srcI[ri]*64 + c0]);
  }
  float acc[4][4]={{0.f}};
  tile_gemm_bf(Ats, Ws, r0, c0, acc);

  const float4 ab4 = *reinterpret_cast<const float4*>(&Ab[c0]);
  const float ab[4]={ab4.x,ab4.y,ab4.z,ab4.w};

  float s1[4]={0.f,0.f,0.f,0.f}, s2[4]={0.f,0.f,0.f,0.f};
  #pragma unroll
  for(int ri=0;ri<4;++ri){
    const float bh[4]={hf2f((us)(bh2[ri].x&0xffff)), hf2f((us)(bh2[ri].x>>16)),
                       hf2f((us)(bh2[ri].y&0xffff)), hf2f((us)(bh2[ri].y>>16))};
    const float ch[4]={hf2f((us)(ch2[ri].x&0xffff)), hf2f((us)(ch2[ri].x>>16)),
                       hf2f((us)(ch2[ri].y&0xffff)), hf2f((us)(ch2[ri].y>>16))};
    float tv[4];
    #pragma unroll
    for(int ci=0;ci<4;++ci){
      float t = acc[ri][ci] + ab[ci] + bh[ci] + ch[ci];
      tv[ci]=t;
      s1[ci]+=t; s2[ci]+=t*t;
    }
    unsigned int p0 = (unsigned int)f2hf(tv[0]) | ((unsigned int)f2hf(tv[1])<<16);
    unsigned int p1 = (unsigned int)f2hf(tv[2]) | ((unsigned int)f2hf(tv[3])<<16);
    *reinterpret_cast<uint2*>(&t16[(size_t)(row0+r0+ri)*64 + c0]) = make_uint2(p0,p1);
  }
  // reduce over the 16-lane tx group (masks 1..8 stay in-group), then one
  // atomic per (group, channel) from tx==0
  #pragma unroll
  for(int m=1;m<16;m<<=1){
    #pragma unroll
    for(int ci=0;ci<4;++ci){
      s1[ci] += __shfl_xor(s1[ci], m);
      s2[ci] += __shfl_xor(s2[ci], m);
    }
  }
  if(tx==0){
    #pragma unroll
    for(int ci=0;ci<4;++ci){
      atomicAdd(&stats[c0+ci],    s1[ci]);
      atomicAdd(&stats[64+c0+ci], s2[ci]);
    }
  }
}

// ---------------------------------------------------------- CSR aggregation + h-BN stats
// one wave per node; 4-wide software pipeline over the edge list
__global__ __launch_bounds__(256) void k_agg(
    const us* __restrict__ e,
    const us* __restrict__ Vh,
    const int* __restrict__ srcP,
    const int* __restrict__ row_ptr,
    const float* __restrict__ invc,
    float* __restrict__ Uh, float* __restrict__ stats)
{
  __shared__ float red[128];
  const int tid=threadIdx.x;
  if(tid<128) red[tid]=0.f;
  __syncthreads();
  const int lane = tid&63;
  const int node = blockIdx.x*4 + (tid>>6);   // 4 waves/block
  const int beg = row_ptr[node];
  const int end = row_ptr[node+1];
  float acc = 0.f;
  int p = beg;
  for(; p+4<=end; p+=4){
    int s0=srcP[p], s1i=srcP[p+1], s2i=srcP[p+2], s3=srcP[p+3];
    float v0=hf2f(Vh[(size_t)s0*64 + lane]);
    float v1=hf2f(Vh[(size_t)s1i*64 + lane]);
    float v2=hf2f(Vh[(size_t)s2i*64 + lane]);
    float v3=hf2f(Vh[(size_t)s3*64 + lane]);
    float e0=bf2f(e[(size_t)(p+0)*64 + lane]);
    float e1=bf2f(e[(size_t)(p+1)*64 + lane]);
    float e2=bf2f(e[(size_t)(p+2)*64 + lane]);
    float e3=bf2f(e[(size_t)(p+3)*64 + lane]);
    acc = fmaf(sigf(e0), v0, acc);
    acc = fmaf(sigf(e1), v1, acc);
    acc = fmaf(sigf(e2), v2, acc);
    acc = fmaf(sigf(e3), v3, acc);
  }
  for(; p<end; ++p){
    int src = srcP[p];
    float g = sigf(bf2f(e[(size_t)p*64 + lane]));
    acc = fmaf(g, hf2f(Vh[(size_t)src*64 + lane]), acc);
  }
  size_t o = (size_t)node*64 + lane;
  float val = Uh[o] + acc*invc[node];
  Uh[o] = val;
  atomicAdd(&red[lane], val);
  atomicAdd(&red[64+lane], val*val);
  __syncthreads();
  if(tid<128) atomicAdd(&stats[128+tid], red[tid]);
}

__global__ void k_node_finB(const float* __restrict__ th, float* __restrict__ h,
                            const float* __restrict__ stats,
                            const float* __restrict__ hg, const float* __restrict__ hb){
  int t = blockIdx.x*256 + threadIdx.x;
  if(t>=NH) return;
  int j=t&63;
  const float invN = 1.0f/(float)NNODE;
  float mean = stats[128+j]*invN;
  float var  = stats[192+j]*invN - mean*mean;
  float rstd = rsqrtf(var + BN_EPS);
  float v = (th[t]-mean)*rstd*hg[j] + hb[j];
  h[t] += fmaxf(v, 0.0f);
}

// ---------------------------------------------------------- edge BN finalize (elementwise)
__global__ __launch_bounds__(256) void k_ebn(
    const us* __restrict__ t16,
    const float* __restrict__ stats,
    const float* __restrict__ eg, const float* __restrict__ eb,
    us* __restrict__ e)
{
  __shared__ float a_s[64], b_s[64];
  const int tid=threadIdx.x;
  if(tid<64){
    const float invE = 1.0f/(float)NEDGE;
    float mean = stats[tid]*invE;
    float var  = stats[64+tid]*invE - mean*mean;
    float rstd = rsqrtf(var + BN_EPS);
    float a = rstd*eg[tid];
    a_s[tid]=a;
    b_s[tid]=eb[tid]-mean*a;
  }
  __syncthreads();
  size_t idx = (size_t)blockIdx.x*256 + tid;   // NE/8 threads
  int j0 = ((int)idx&7)<<3;
  const short8v tv = *reinterpret_cast<const short8v*>(&t16[idx*8]);
  const short8v ev = *reinterpret_cast<const short8v*>(&e[idx*8]);
  short8v ov;
  #pragma unroll
  for(int j=0;j<8;++j){
    float tt = hf2f((us)tv[j]);
    float v  = tt*a_s[j0+j] + b_s[j0+j];
    float o  = bf2f((us)ev[j]) + fmaxf(v, 0.0f);
    ov[j] = (short)f2bf(o);
  }
  *reinterpret_cast<short8v*>(&e[idx*8]) = ov;
}

// ---------------------------------------------------------- final MLP (fused)
__global__ __launch_bounds__(256) void k_mlp(
    const us* __restrict__ e,
    const int* __restrict__ eidP,
    const float* __restrict__ f1w, const float* __restrict__ f1b,
    const float* __restrict__ f2w, const float* __restrict__ f2b,
    const float* __restrict__ f3w, const float* __restrict__ f3b,
    float* __restrict__ out)
{
  __shared__ float At[64][68];
  __shared__ float Ws[64][68];
  __shared__ float ored[64];
  const int tid=threadIdx.x;
  const int row0 = blockIdx.x*64;
  if(tid<64) ored[tid]=0.f;
  stage_At_bf16(At, e, row0, tid);
  stage_W(Ws, f1w, tid);
  __syncthreads();
  const int tx=tid&15, ty=tid>>4, r0=tx<<2, c0=ty<<2;
  float acc[4][4]={{0.f}};
  tile_gemm(At, Ws, r0, c0, acc);
  const float4 b14 = *reinterpret_cast<const float4*>(&f1b[c0]);
  const float b1[4]={b14.x,b14.y,b14.z,b14.w};
  float z1[4][4];
  #pragma unroll
  for(int ri=0;ri<4;++ri)
    #pragma unroll
    for(int ci=0;ci<4;++ci){
      float v = acc[ri][ci]+b1[ci];
      z1[ri][ci] = v*sigf(v);
    }
  __syncthreads();
  #pragma unroll
  for(int ri=0;ri<4;++ri)
    #pragma unroll
    for(int ci=0;ci<4;++ci)
      At[c0+ci][r0+ri] = z1[ri][ci];
  stage_W(Ws, f2w, tid);
  __syncthreads();
  float acc2[4][4]={{0.f}};
  tile_gemm(At, Ws, r0, c0, acc2);
  const float4 b24 = *reinterpret_cast<const float4*>(&f2b[c0]);
  const float b2[4]={b24.x,b24.y,b24.z,b24.w};
  const float4 w34 = *reinterpret_cast<const float4*>(&f3w[c0]);
  const float w3[4]={w34.x,w34.y,w34.z,w34.w};
  float part[4]={0.f,0.f,0.f,0.f};
  #pragma unroll
  for(int ri=0;ri<4;++ri)
    #pragma unroll
    for(int ci=0;ci<4;++ci){
      float v = acc2[ri][ci]+b2[ci];
      float z = v*sigf(v);
      part[ri] += z*w3[ci];
    }
  #pragma unroll
  for(int ri=0;ri<4;++ri) atomicAdd(&ored[r0+ri], part[ri]);
  __syncthreads();
  if(tid<64) out[eidP[row0+tid]] = sigf(ored[tid] + f3b[0]);
}

// ---------------------------------------------------------------- launch
extern "C" void kernel_launch(void* const* d_in, const int* in_sizes, int n_in,
                              void* d_out, int out_size, void* d_ws, size_t ws_size,
                              hipStream_t stream){
  const float* x    = (const float*)d_in[0];
  const float* ea   = (const float*)d_in[1];
  const int*   ei   = (const int*)  d_in[2];
  const float* hp_w = (const float*)d_in[3];
  const float* hp_b = (const float*)d_in[4];
  const float* ep_w = (const float*)d_in[5];
  const float* ep_b = (const float*)d_in[6];
  const float* Uw   = (const float*)d_in[7];
  const float* Ub   = (const float*)d_in[8];
  const float* Vw   = (const float*)d_in[9];
  const float* Vb   = (const float*)d_in[10];
  const float* Aw   = (const float*)d_in[11];
  const float* Ab   = (const float*)d_in[12];
  const float* Bw   = (const float*)d_in[13];
  const float* Bb   = (const float*)d_in[14];
  const float* Cw   = (const float*)d_in[15];
  const float* Cb   = (const float*)d_in[16];
  const float* hg   = (const float*)d_in[17];
  const float* hb   = (const float*)d_in[18];
  const float* eg   = (const float*)d_in[19];
  const float* eb   = (const float*)d_in[20];
  const float* f1w  = (const float*)d_in[21];
  const float* f1b  = (const float*)d_in[22];
  const float* f2w  = (const float*)d_in[23];
  const float* f2b  = (const float*)d_in[24];
  const float* f3w  = (const float*)d_in[25];
  const float* f3b  = (const float*)d_in[26];

  // ws: e(bf16) | t(f16) | h(f32) | Uh(f32) | stats | Vh/Bh/Ch(f16) | int arrays
  char* base = (char*)d_ws;
  us* e    = (us*)base;                               // 102.4 MB
  us* t16  = (us*)(base + (size_t)NE*2);              // 102.4 MB
  float* h  = (float*)(base + 2ull*NE*2);             // 12.8 MB
  float* Uh = h + (size_t)NH;                         // 12.8 MB
  float* stats = Uh + (size_t)NH;                     // 1 KB
  us* Vh = (us*)(stats + 256);                        // 6.4 MB
  us* Bh = Vh + (size_t)NH;                           // 6.4 MB
  us* Ch = Bh + (size_t)NH;                           // 6.4 MB
  int* cnt     = (int*)(Ch + (size_t)NH);             // 0.2 MB
  float* invc  = (float*)(cnt + NNODE);
  int* row_ptr = (int*)(invc + NNODE);
  int* cursor  = row_ptr + NNODE + 1;
  int* eidP    = cursor + NNODE;                      // 3.2 MB
  int* dstP    = eidP + NEDGE;                        // 3.2 MB
  int* srcP    = dstP + NEDGE;                        // 3.2 MB
  // total ≈ 260.0 MB

  dim3 blk(256);
  k_zero_i<<<dim3((NNODE+255)/256), blk, 0, stream>>>(cnt, NNODE);
  k_count <<<dim3((NEDGE+255)/256), blk, 0, stream>>>(ei, cnt);
  k_inv   <<<dim3((NNODE+255)/256), blk, 0, stream>>>(cnt, invc);
  k_scan  <<<dim3(1), blk, 0, stream>>>(cnt, row_ptr, cursor);
  k_fill  <<<dim3((NEDGE+255)/256), blk, 0, stream>>>(ei, cursor, eidP);
  k_perm  <<<dim3((NEDGE+255)/256), blk, 0, stream>>>(ei, eidP, dstP, srcP);
  k_init_h<<<dim3((NH+255)/256), blk, 0, stream>>>(x, hp_w, hp_b, h);
  k_init_e<<<dim3((NE/2+255)/256), blk, 0, stream>>>(ea, eidP, ep_w, ep_b, e);

  for(int l=0;l<NLAYER;++l){
    k_zero_stats<<<dim3(1), blk, 0, stream>>>(stats);
    k_node_gemm<<<dim3((NNODE+63)/64), blk, 0, stream>>>(h,
        Uw+l*4096, Ub+l*64, Vw+l*4096, Vb+l*64,
        Bw+l*4096, Bb+l*64, Cw+l*4096, Cb+l*64,
        Uh, Vh, Bh, Ch);
    k_edge_A<<<dim3(NEDGE/64), blk, 0, stream>>>(e, Aw+l*4096, Ab+l*64,
        Bh, Ch, dstP, srcP, t16, stats);
    k_agg<<<dim3(NNODE/4), blk, 0, stream>>>(e, Vh, srcP, row_ptr,
        invc, Uh, stats);
    k_node_finB<<<dim3(NH/256), blk, 0, stream>>>(Uh, h, stats, hg+l*64, hb+l*64);
    k_ebn<<<dim3(NE/8/256), blk, 0, stream>>>(t16, stats, eg+l*64, eb+l*64, e);
  }
  k_mlp<<<dim3(NEDGE/64), blk, 0, stream>>>(e, eidP, f1w, f1b, f2w, f2b,
                                            f3w, f3b, (float*)d_out);
}

// Round 11
// 2356.330 us; speedup vs baseline: 3.0538x; 3.0538x over previous
//
#include <hip/hip_runtime.h>

#define NNODE 50000
#define NEDGE 800000
#define NLAYER 4
#define BN_EPS 1e-5f

#define NH (NNODE*64)   // 3,200,000
#define NE (NEDGE*64)   // 51,200,000
#define NBUCKET 256

typedef __attribute__((ext_vector_type(8))) short short8v;
typedef unsigned short us;

__device__ __forceinline__ float sigf(float x){ return 1.0f/(1.0f+__expf(-x)); }

__device__ __forceinline__ float bf2f(us u){
  union { unsigned int i; float f; } c; c.i = ((unsigned int)u)<<16; return c.f;
}
__device__ __forceinline__ us f2bf(float f){
  union { float f; unsigned int i; } c; c.f = f;
  unsigned int r = c.i + 0x7FFFu + ((c.i>>16)&1u);   // RNE
  return (us)(r>>16);
}
__device__ __forceinline__ float hf2f(us u){
  union { us u; _Float16 h; } c; c.u=u; return (float)c.h;
}
__device__ __forceinline__ us f2hf(float f){
  union { us u; _Float16 h; } c; c.h=(_Float16)f; return c.u;
}

// ---------------------------------------------------------------- utility
__global__ void k_zero_i(int* __restrict__ p, int n){
  int i = blockIdx.x*256 + threadIdx.x;
  if(i<n) p[i]=0;
}
__global__ void k_zero_f(float* __restrict__ p, int n){
  int i = blockIdx.x*256 + threadIdx.x;
  if(i<n) p[i]=0.f;
}
__global__ void k_count(const int* __restrict__ ei, int* __restrict__ cnt){
  int i = blockIdx.x*256 + threadIdx.x;
  if(i<NEDGE) atomicAdd(&cnt[ei[i]], 1);   // ei[0][i] = dst
}
__global__ void k_inv(const int* __restrict__ cnt, float* __restrict__ invc){
  int i = blockIdx.x*256 + threadIdx.x;
  if(i<NNODE){ int c=cnt[i]; invc[i] = 1.0f/(float)(c<1?1:c); }
}

__global__ void k_scan(const int* __restrict__ cnt, int* __restrict__ row_ptr,
                       int* __restrict__ cursor){
  __shared__ int buf[256];
  __shared__ int carry;
  const int tid = threadIdx.x;
  if(tid==0) carry=0;
  __syncthreads();
  for(int base=0; base<NNODE; base+=256){
    int i = base+tid;
    int v = (i<NNODE)? cnt[i] : 0;
    buf[tid]=v; __syncthreads();
    #pragma unroll
    for(int off=1; off<256; off<<=1){
      int t = (tid>=off)? buf[tid-off] : 0;
      __syncthreads();
      buf[tid]+=t;
      __syncthreads();
    }
    int excl = carry + buf[tid]-v;
    if(i<NNODE){ row_ptr[i]=excl; cursor[i]=excl; }
    __syncthreads();
    if(tid==0) carry += buf[255];
    __syncthreads();
  }
  if(tid==0) row_ptr[NNODE]=carry;
}

__global__ void k_fill(const int* __restrict__ ei, int* __restrict__ cursor,
                       int* __restrict__ eidP){
  int i = blockIdx.x*256 + threadIdx.x;
  if(i<NEDGE){
    int pos = atomicAdd(&cursor[ei[i]], 1);
    eidP[pos] = i;
  }
}

__global__ void k_perm(const int* __restrict__ ei, const int* __restrict__ eidP,
                       int* __restrict__ dstP, int* __restrict__ srcP){
  int p = blockIdx.x*256 + threadIdx.x;
  if(p<NEDGE){
    int eid = eidP[p];
    dstP[p] = ei[eid];
    srcP[p] = ei[NEDGE+eid];
  }
}

__global__ void k_init_h(const float* __restrict__ x, const float* __restrict__ w,
                         const float* __restrict__ b, float* __restrict__ h){
  int t = blockIdx.x*256 + threadIdx.x;
  if(t>=NH) return;
  int i=t>>6, j=t&63;
  float v = x[2*i]*w[j] + x[2*i+1]*w[64+j] + b[j];
  h[t] = fmaxf(v, 0.0f);
}

__global__ void k_init_e(const float* __restrict__ ea, const int* __restrict__ eidP,
                         const float* __restrict__ w, const float* __restrict__ b,
                         us* __restrict__ e){
  int t = blockIdx.x*256 + threadIdx.x;      // pair index
  if(t >= NE/2) return;
  int p = t>>5;          // slot
  int j = (t&31)<<1;
  float a = ea[eidP[p]];
  float v0 = fmaxf(a*w[j]   + b[j],   0.f);
  float v1 = fmaxf(a*w[j+1] + b[j+1], 0.f);
  unsigned int pk = (unsigned int)f2bf(v0) | ((unsigned int)f2bf(v1)<<16);
  *reinterpret_cast<unsigned int*>(&e[2*t]) = pk;
}

// ------------------------------------------------------------ tile helpers
__device__ __forceinline__ void tile_gemm(const float (&At)[64][68], const float (&Ws)[64][68],
                                          int r0, int c0, float (&acc)[4][4]){
  #pragma unroll 4
  for(int k=0;k<64;++k){
    const float4 a = *reinterpret_cast<const float4*>(&At[k][r0]);
    const float4 b = *reinterpret_cast<const float4*>(&Ws[k][c0]);
    const float av[4]={a.x,a.y,a.z,a.w};
    const float bv[4]={b.x,b.y,b.z,b.w};
    #pragma unroll
    for(int ri=0;ri<4;++ri)
      #pragma unroll
      for(int ci=0;ci<4;++ci)
        acc[ri][ci] = fmaf(av[ri], bv[ci], acc[ri][ci]);
  }
}

__device__ __forceinline__ void stage_At_f32(float (&At)[64][68], const float* __restrict__ src,
                                             int row0, int rowmax, int tid){
  for(int it=0; it<4; ++it){
    int idx = tid + it*256;
    int r = idx>>4, c4=(idx&15)<<2;
    int gr = row0 + r;
    float4 v = make_float4(0.f,0.f,0.f,0.f);
    if(gr < rowmax) v = *reinterpret_cast<const float4*>(&src[(size_t)gr*64 + c4]);
    At[c4+0][r]=v.x; At[c4+1][r]=v.y; At[c4+2][r]=v.z; At[c4+3][r]=v.w;
  }
}

__device__ __forceinline__ void stage_At_bf16(float (&At)[64][68], const us* __restrict__ src,
                                              int row0, int tid){
  #pragma unroll
  for(int it=0; it<2; ++it){
    int idx = tid + it*256;          // 0..511
    int r = idx>>3, c8 = (idx&7)<<3;
    int gr = row0 + r;
    const short8v v = *reinterpret_cast<const short8v*>(&src[(size_t)gr*64 + c8]);
    #pragma unroll
    for(int j=0;j<8;++j) At[c8+j][r] = bf2f((us)v[j]);
  }
}

__device__ __forceinline__ void stage_W(float (&Ws)[64][68], const float* __restrict__ W, int tid){
  for(int it=0; it<4; ++it){
    int idx = tid + it*256;
    int k = idx>>4, c4=(idx&15)<<2;
    *reinterpret_cast<float4*>(&Ws[k][c4]) = *reinterpret_cast<const float4*>(&W[k*64+c4]);
  }
}

// ---------------------------------------------------------- node GEMMs
__device__ __forceinline__ void node_one_mat_f32(float (&At)[64][68], float (&Ws)[64][68],
    const float* __restrict__ W, const float* __restrict__ B, float* __restrict__ O,
    int row0, int tid){
  __syncthreads();
  stage_W(Ws, W, tid);
  __syncthreads();
  const int tx=tid&15, ty=tid>>4, r0=tx<<2, c0=ty<<2;
  float acc[4][4]={{0.f}};
  tile_gemm(At, Ws, r0, c0, acc);
  const float4 b4 = *reinterpret_cast<const float4*>(&B[c0]);
  const float bb[4]={b4.x,b4.y,b4.z,b4.w};
  #pragma unroll
  for(int ri=0;ri<4;++ri){
    int gr = row0 + r0 + ri;
    if(gr < NNODE){
      float4 o = make_float4(acc[ri][0]+bb[0], acc[ri][1]+bb[1],
                             acc[ri][2]+bb[2], acc[ri][3]+bb[3]);
      *reinterpret_cast<float4*>(&O[(size_t)gr*64 + c0]) = o;
    }
  }
}

__device__ __forceinline__ void node_one_mat_f16(float (&At)[64][68], float (&Ws)[64][68],
    const float* __restrict__ W, const float* __restrict__ B, us* __restrict__ O,
    int row0, int tid){
  __syncthreads();
  stage_W(Ws, W, tid);
  __syncthreads();
  const int tx=tid&15, ty=tid>>4, r0=tx<<2, c0=ty<<2;
  float acc[4][4]={{0.f}};
  tile_gemm(At, Ws, r0, c0, acc);
  const float4 b4 = *reinterpret_cast<const float4*>(&B[c0]);
  const float bb[4]={b4.x,b4.y,b4.z,b4.w};
  #pragma unroll
  for(int ri=0;ri<4;++ri){
    int gr = row0 + r0 + ri;
    if(gr < NNODE){
      unsigned int p0 = (unsigned int)f2hf(acc[ri][0]+bb[0]) | ((unsigned int)f2hf(acc[ri][1]+bb[1])<<16);
      unsigned int p1 = (unsigned int)f2hf(acc[ri][2]+bb[2]) | ((unsigned int)f2hf(acc[ri][3]+bb[3])<<16);
      *reinterpret_cast<uint2*>(&O[(size_t)gr*64 + c0]) = make_uint2(p0,p1);
    }
  }
}

__global__ __launch_bounds__(256) void k_node_gemm(
    const float* __restrict__ h,
    const float* __restrict__ Uw, const float* __restrict__ Ub,
    const float* __restrict__ Vw, const float* __restrict__ Vb,
    const float* __restrict__ Bw, const float* __restrict__ Bb,
    const float* __restrict__ Cw, const float* __restrict__ Cb,
    float* __restrict__ Uh, us* __restrict__ Vh,
    us* __restrict__ Bh, us* __restrict__ Ch)
{
  __shared__ float At[64][68];
  __shared__ float Ws[64][68];
  const int tid = threadIdx.x;
  const int row0 = blockIdx.x*64;
  stage_At_f32(At, h, row0, NNODE, tid);
  node_one_mat_f32(At, Ws, Uw, Ub, Uh, row0, tid);
  node_one_mat_f16(At, Ws, Vw, Vb, Vh, row0, tid);
  node_one_mat_f16(At, Ws, Bw, Bb, Bh, row0, tid);
  node_one_mat_f16(At, Ws, Cw, Cb, Ch, row0, tid);
}

// ---------------------------------------------------------- edge pass A
// round-9 structure; stats go to per-bucket arrays (low contention)
__global__ __launch_bounds__(256) void k_edge_A(
    const us* __restrict__ e,
    const float* __restrict__ Aw, const float* __restrict__ Ab,
    const us* __restrict__ Bh, const us* __restrict__ Ch,
    const int* __restrict__ dstP, const int* __restrict__ srcP,
    us* __restrict__ t16, float* __restrict__ buckets)
{
  __shared__ float At[64][68];
  __shared__ float Ws[64][68];
  __shared__ float red[128];
  const int tid=threadIdx.x;
  const int row0 = blockIdx.x*64;
  if(tid<128) red[tid]=0.f;
  stage_At_bf16(At, e, row0, tid);
  stage_W(Ws, Aw, tid);
  __syncthreads();
  const int tx=tid&15, ty=tid>>4, r0=tx<<2, c0=ty<<2;
  float acc[4][4]={{0.f}};
  tile_gemm(At, Ws, r0, c0, acc);

  int dstI[4], srcI[4];
  #pragma unroll
  for(int ri=0;ri<4;++ri){
    dstI[ri]=dstP[row0+r0+ri];
    srcI[ri]=srcP[row0+r0+ri];
  }
  const float4 ab4 = *reinterpret_cast<const float4*>(&Ab[c0]);
  const float ab[4]={ab4.x,ab4.y,ab4.z,ab4.w};

  float s1[4]={0.f,0.f,0.f,0.f}, s2[4]={0.f,0.f,0.f,0.f};
  #pragma unroll
  for(int ri=0;ri<4;++ri){
    const uint2 b2 = *reinterpret_cast<const uint2*>(&Bh[(size_t)dstI[ri]*64 + c0]);
    const uint2 c2 = *reinterpret_cast<const uint2*>(&Ch[(size_t)srcI[ri]*64 + c0]);
    const float bh[4]={hf2f((us)(b2.x&0xffff)), hf2f((us)(b2.x>>16)),
                       hf2f((us)(b2.y&0xffff)), hf2f((us)(b2.y>>16))};
    const float ch[4]={hf2f((us)(c2.x&0xffff)), hf2f((us)(c2.x>>16)),
                       hf2f((us)(c2.y&0xffff)), hf2f((us)(c2.y>>16))};
    float tv[4];
    #pragma unroll
    for(int ci=0;ci<4;++ci){
      float t = acc[ri][ci] + ab[ci] + bh[ci] + ch[ci];
      tv[ci]=t;
      s1[ci]+=t; s2[ci]+=t*t;
    }
    unsigned int p0 = (unsigned int)f2hf(tv[0]) | ((unsigned int)f2hf(tv[1])<<16);
    unsigned int p1 = (unsigned int)f2hf(tv[2]) | ((unsigned int)f2hf(tv[3])<<16);
    *reinterpret_cast<uint2*>(&t16[(size_t)(row0+r0+ri)*64 + c0]) = make_uint2(p0,p1);
  }
  #pragma unroll
  for(int ci=0;ci<4;++ci){
    atomicAdd(&red[c0+ci],    s1[ci]);
    atomicAdd(&red[64+c0+ci], s2[ci]);
  }
  __syncthreads();
  float* bk = buckets + (size_t)(blockIdx.x & (NBUCKET-1))*256;
  if(tid<128) atomicAdd(&bk[tid], red[tid]);
}

// ---------------------------------------------------------- CSR aggregation + h-BN stats
__global__ __launch_bounds__(256) void k_agg(
    const us* __restrict__ e,
    const us* __restrict__ Vh,
    const int* __restrict__ srcP,
    const int* __restrict__ row_ptr,
    const float* __restrict__ invc,
    float* __restrict__ Uh, float* __restrict__ buckets)
{
  __shared__ float red[128];
  const int tid=threadIdx.x;
  if(tid<128) red[tid]=0.f;
  __syncthreads();
  const int lane = tid&63;
  const int node = blockIdx.x*4 + (tid>>6);   // 4 waves/block
  const int beg = row_ptr[node];
  const int end = row_ptr[node+1];
  float acc = 0.f;
  int p = beg;
  for(; p+4<=end; p+=4){
    int s0=srcP[p], s1i=srcP[p+1], s2i=srcP[p+2], s3=srcP[p+3];
    float v0=hf2f(Vh[(size_t)s0*64 + lane]);
    float v1=hf2f(Vh[(size_t)s1i*64 + lane]);
    float v2=hf2f(Vh[(size_t)s2i*64 + lane]);
    float v3=hf2f(Vh[(size_t)s3*64 + lane]);
    float e0=bf2f(e[(size_t)(p+0)*64 + lane]);
    float e1=bf2f(e[(size_t)(p+1)*64 + lane]);
    float e2=bf2f(e[(size_t)(p+2)*64 + lane]);
    float e3=bf2f(e[(size_t)(p+3)*64 + lane]);
    acc = fmaf(sigf(e0), v0, acc);
    acc = fmaf(sigf(e1), v1, acc);
    acc = fmaf(sigf(e2), v2, acc);
    acc = fmaf(sigf(e3), v3, acc);
  }
  for(; p<end; ++p){
    int src = srcP[p];
    float g = sigf(bf2f(e[(size_t)p*64 + lane]));
    acc = fmaf(g, hf2f(Vh[(size_t)src*64 + lane]), acc);
  }
  size_t o = (size_t)node*64 + lane;
  float val = Uh[o] + acc*invc[node];
  Uh[o] = val;
  atomicAdd(&red[lane], val);
  atomicAdd(&red[64+lane], val*val);
  __syncthreads();
  float* bk = buckets + (size_t)(blockIdx.x & (NBUCKET-1))*256;
  if(tid<128) atomicAdd(&bk[128+tid], red[tid]);
}

// ---------------------------------------------------------- bucket reduce
// one block, 256 threads: stats[t] = sum over buckets[b][t]
__global__ void k_redstats(const float* __restrict__ buckets, float* __restrict__ stats){
  const int tid = threadIdx.x;
  float s = 0.f;
  for(int b=0;b<NBUCKET;++b) s += buckets[(size_t)b*256 + tid];
  stats[tid] = s;
}

__global__ void k_node_finB(const float* __restrict__ th, float* __restrict__ h,
                            const float* __restrict__ stats,
                            const float* __restrict__ hg, const float* __restrict__ hb){
  int t = blockIdx.x*256 + threadIdx.x;
  if(t>=NH) return;
  int j=t&63;
  const float invN = 1.0f/(float)NNODE;
  float mean = stats[128+j]*invN;
  float var  = stats[192+j]*invN - mean*mean;
  float rstd = rsqrtf(var + BN_EPS);
  float v = (th[t]-mean)*rstd*hg[j] + hb[j];
  h[t] += fmaxf(v, 0.0f);
}

// ---------------------------------------------------------- edge BN finalize
__global__ __launch_bounds__(256) void k_ebn(
    const us* __restrict__ t16,
    const float* __restrict__ stats,
    const float* __restrict__ eg, const float* __restrict__ eb,
    us* __restrict__ e)
{
  __shared__ float a_s[64], b_s[64];
  const int tid=threadIdx.x;
  if(tid<64){
    const float invE = 1.0f/(float)NEDGE;
    float mean = stats[tid]*invE;
    float var  = stats[64+tid]*invE - mean*mean;
    float rstd = rsqrtf(var + BN_EPS);
    float a = rstd*eg[tid];
    a_s[tid]=a;
    b_s[tid]=eb[tid]-mean*a;
  }
  __syncthreads();
  size_t idx = (size_t)blockIdx.x*256 + tid;   // NE/8 threads
  int j0 = ((int)idx&7)<<3;
  const short8v tv = *reinterpret_cast<const short8v*>(&t16[idx*8]);
  const short8v ev = *reinterpret_cast<const short8v*>(&e[idx*8]);
  short8v ov;
  #pragma unroll
  for(int j=0;j<8;++j){
    float tt = hf2f((us)tv[j]);
    float v  = tt*a_s[j0+j] + b_s[j0+j];
    float o  = bf2f((us)ev[j]) + fmaxf(v, 0.0f);
    ov[j] = (short)f2bf(o);
  }
  *reinterpret_cast<short8v*>(&e[idx*8]) = ov;
}

// ---------------------------------------------------------- final MLP (fused)
__global__ __launch_bounds__(256) void k_mlp(
    const us* __restrict__ e,
    const int* __restrict__ eidP,
    const float* __restrict__ f1w, const float* __restrict__ f1b,
    const float* __restrict__ f2w, const float* __restrict__ f2b,
    const float* __restrict__ f3w, const float* __restrict__ f3b,
    float* __restrict__ out)
{
  __shared__ float At[64][68];
  __shared__ float Ws[64][68];
  __shared__ float ored[64];
  const int tid=threadIdx.x;
  const int row0 = blockIdx.x*64;
  if(tid<64) ored[tid]=0.f;
  stage_At_bf16(At, e, row0, tid);
  stage_W(Ws, f1w, tid);
  __syncthreads();
  const int tx=tid&15, ty=tid>>4, r0=tx<<2, c0=ty<<2;
  float acc[4][4]={{0.f}};
  tile_gemm(At, Ws, r0, c0, acc);
  const float4 b14 = *reinterpret_cast<const float4*>(&f1b[c0]);
  const float b1[4]={b14.x,b14.y,b14.z,b14.w};
  float z1[4][4];
  #pragma unroll
  for(int ri=0;ri<4;++ri)
    #pragma unroll
    for(int ci=0;ci<4;++ci){
      float v = acc[ri][ci]+b1[ci];
      z1[ri][ci] = v*sigf(v);
    }
  __syncthreads();
  #pragma unroll
  for(int ri=0;ri<4;++ri)
    #pragma unroll
    for(int ci=0;ci<4;++ci)
      At[c0+ci][r0+ri] = z1[ri][ci];
  stage_W(Ws, f2w, tid);
  __syncthreads();
  float acc2[4][4]={{0.f}};
  tile_gemm(At, Ws, r0, c0, acc2);
  const float4 b24 = *reinterpret_cast<const float4*>(&f2b[c0]);
  const float b2[4]={b24.x,b24.y,b24.z,b24.w};
  const float4 w34 = *reinterpret_cast<const float4*>(&f3w[c0]);
  const float w3[4]={w34.x,w34.y,w34.z,w34.w};
  float part[4]={0.f,0.f,0.f,0.f};
  #pragma unroll
  for(int ri=0;ri<4;++ri)
    #pragma unroll
    for(int ci=0;ci<4;++ci){
      float v = acc2[ri][ci]+b2[ci];
      float z = v*sigf(v);
      part[ri] += z*w3[ci];
    }
  #pragma unroll
  for(int ri=0;ri<4;++ri) atomicAdd(&ored[r0+ri], part[ri]);
  __syncthreads();
  if(tid<64) out[eidP[row0+tid]] = sigf(ored[tid] + f3b[0]);
}

// ---------------------------------------------------------------- launch
extern "C" void kernel_launch(void* const* d_in, const int* in_sizes, int n_in,
                              void* d_out, int out_size, void* d_ws, size_t ws_size,
                              hipStream_t stream){
  const float* x    = (const float*)d_in[0];
  const float* ea   = (const float*)d_in[1];
  const int*   ei   = (const int*)  d_in[2];
  const float* hp_w = (const float*)d_in[3];
  const float* hp_b = (const float*)d_in[4];
  const float* ep_w = (const float*)d_in[5];
  const float* ep_b = (const float*)d_in[6];
  const float* Uw   = (const float*)d_in[7];
  const float* Ub   = (const float*)d_in[8];
  const float* Vw   = (const float*)d_in[9];
  const float* Vb   = (const float*)d_in[10];
  const float* Aw   = (const float*)d_in[11];
  const float* Ab   = (const float*)d_in[12];
  const float* Bw   = (const float*)d_in[13];
  const float* Bb   = (const float*)d_in[14];
  const float* Cw   = (const float*)d_in[15];
  const float* Cb   = (const float*)d_in[16];
  const float* hg   = (const float*)d_in[17];
  const float* hb   = (const float*)d_in[18];
  const float* eg   = (const float*)d_in[19];
  const float* eb   = (const float*)d_in[20];
  const float* f1w  = (const float*)d_in[21];
  const float* f1b  = (const float*)d_in[22];
  const float* f2w  = (const float*)d_in[23];
  const float* f2b  = (const float*)d_in[24];
  const float* f3w  = (const float*)d_in[25];
  const float* f3b  = (const float*)d_in[26];

  // ws: e(bf16) | t(f16) | h(f32) | Uh(f32) | stats | buckets | Vh/Bh/Ch(f16) | int arrays
  char* base = (char*)d_ws;
  us* e    = (us*)base;                               // 102.4 MB
  us* t16  = (us*)(base + (size_t)NE*2);              // 102.4 MB
  float* h  = (float*)(base + 2ull*NE*2);             // 12.8 MB
  float* Uh = h + (size_t)NH;                         // 12.8 MB
  float* stats = Uh + (size_t)NH;                     // 1 KB
  float* buckets = stats + 256;                       // 256 KB (256x256)
  us* Vh = (us*)(buckets + NBUCKET*256);              // 6.4 MB
  us* Bh = Vh + (size_t)NH;                           // 6.4 MB
  us* Ch = Bh + (size_t)NH;                           // 6.4 MB
  int* cnt     = (int*)(Ch + (size_t)NH);             // 0.2 MB
  float* invc  = (float*)(cnt + NNODE);
  int* row_ptr = (int*)(invc + NNODE);
  int* cursor  = row_ptr + NNODE + 1;
  int* eidP    = cursor + NNODE;                      // 3.2 MB
  int* dstP    = eidP + NEDGE;                        // 3.2 MB
  int* srcP    = dstP + NEDGE;                        // 3.2 MB
  // total ≈ 260.3 MB

  dim3 blk(256);
  k_zero_i<<<dim3((NNODE+255)/256), blk, 0, stream>>>(cnt, NNODE);
  k_count <<<dim3((NEDGE+255)/256), blk, 0, stream>>>(ei, cnt);
  k_inv   <<<dim3((NNODE+255)/256), blk, 0, stream>>>(cnt, invc);
  k_scan  <<<dim3(1), blk, 0, stream>>>(cnt, row_ptr, cursor);
  k_fill  <<<dim3((NEDGE+255)/256), blk, 0, stream>>>(ei, cursor, eidP);
  k_perm  <<<dim3((NEDGE+255)/256), blk, 0, stream>>>(ei, eidP, dstP, srcP);
  k_init_h<<<dim3((NH+255)/256), blk, 0, stream>>>(x, hp_w, hp_b, h);
  k_init_e<<<dim3((NE/2+255)/256), blk, 0, stream>>>(ea, eidP, ep_w, ep_b, e);

  for(int l=0;l<NLAYER;++l){
    k_zero_f<<<dim3(NBUCKET*256/256), blk, 0, stream>>>(buckets, NBUCKET*256);
    k_node_gemm<<<dim3((NNODE+63)/64), blk, 0, stream>>>(h,
        Uw+l*4096, Ub+l*64, Vw+l*4096, Vb+l*64,
        Bw+l*4096, Bb+l*64, Cw+l*4096, Cb+l*64,
        Uh, Vh, Bh, Ch);
    k_edge_A<<<dim3(NEDGE/64), blk, 0, stream>>>(e, Aw+l*4096, Ab+l*64,
        Bh, Ch, dstP, srcP, t16, buckets);
    k_agg<<<dim3(NNODE/4), blk, 0, stream>>>(e, Vh, srcP, row_ptr,
        invc, Uh, buckets);
    k_redstats<<<dim3(1), blk, 0, stream>>>(buckets, stats);
    k_node_finB<<<dim3(NH/256), blk, 0, stream>>>(Uh, h, stats, hg+l*64, hb+l*64);
    k_ebn<<<dim3(NE/8/256), blk, 0, stream>>>(t16, stats, eg+l*64, eb+l*64, e);
  }
  k_mlp<<<dim3(NEDGE/64), blk, 0, stream>>>(e, eidP, f1w, f1b, f2w, f2b,
                                            f3w, f3b, (float*)d_out);
}

// Round 15
// 2344.723 us; speedup vs baseline: 3.0689x; 1.0050x over previous
//
#include <hip/hip_runtime.h>

#define NNODE 50000
#define NEDGE 800000
#define NLAYER 4
#define BN_EPS 1e-5f

#define NH (NNODE*64)   // 3,200,000
#define NE (NEDGE*64)   // 51,200,000
#define NBUCKET 256

typedef __attribute__((ext_vector_type(8))) short short8v;
typedef unsigned short us;

__device__ __forceinline__ float sigf(float x){ return 1.0f/(1.0f+__expf(-x)); }

__device__ __forceinline__ float bf2f(us u){
  union { unsigned int i; float f; } c; c.i = ((unsigned int)u)<<16; return c.f;
}
__device__ __forceinline__ us f2bf(float f){
  union { float f; unsigned int i; } c; c.f = f;
  unsigned int r = c.i + 0x7FFFu + ((c.i>>16)&1u);   // RNE
  return (us)(r>>16);
}
__device__ __forceinline__ float hf2f(us u){
  union { us u; _Float16 h; } c; c.u=u; return (float)c.h;
}
__device__ __forceinline__ us f2hf(float f){
  union { us u; _Float16 h; } c; c.h=(_Float16)f; return c.u;
}

// ---------------------------------------------------------------- utility
__global__ void k_zero_i(int* __restrict__ p, int n){
  int i = blockIdx.x*256 + threadIdx.x;
  if(i<n) p[i]=0;
}
__global__ void k_zero_f(float* __restrict__ p, int n){
  int i = blockIdx.x*256 + threadIdx.x;
  if(i<n) p[i]=0.f;
}
__global__ void k_count(const int* __restrict__ ei, int* __restrict__ cnt){
  int i = blockIdx.x*256 + threadIdx.x;
  if(i<NEDGE) atomicAdd(&cnt[ei[i]], 1);   // ei[0][i] = dst
}
__global__ void k_inv(const int* __restrict__ cnt, float* __restrict__ invc){
  int i = blockIdx.x*256 + threadIdx.x;
  if(i<NNODE){ int c=cnt[i]; invc[i] = 1.0f/(float)(c<1?1:c); }
}

__global__ void k_scan(const int* __restrict__ cnt, int* __restrict__ row_ptr,
                       int* __restrict__ cursor){
  __shared__ int buf[256];
  __shared__ int carry;
  const int tid = threadIdx.x;
  if(tid==0) carry=0;
  __syncthreads();
  for(int base=0; base<NNODE; base+=256){
    int i = base+tid;
    int v = (i<NNODE)? cnt[i] : 0;
    buf[tid]=v; __syncthreads();
    #pragma unroll
    for(int off=1; off<256; off<<=1){
      int t = (tid>=off)? buf[tid-off] : 0;
      __syncthreads();
      buf[tid]+=t;
      __syncthreads();
    }
    int excl = carry + buf[tid]-v;
    if(i<NNODE){ row_ptr[i]=excl; cursor[i]=excl; }
    __syncthreads();
    if(tid==0) carry += buf[255];
    __syncthreads();
  }
  if(tid==0) row_ptr[NNODE]=carry;
}

__global__ void k_fill(const int* __restrict__ ei, int* __restrict__ cursor,
                       int* __restrict__ eidP){
  int i = blockIdx.x*256 + threadIdx.x;
  if(i<NEDGE){
    int pos = atomicAdd(&cursor[ei[i]], 1);
    eidP[pos] = i;
  }
}

__global__ void k_perm(const int* __restrict__ ei, const int* __restrict__ eidP,
                       int* __restrict__ dstP, int* __restrict__ srcP){
  int p = blockIdx.x*256 + threadIdx.x;
  if(p<NEDGE){
    int eid = eidP[p];
    dstP[p] = ei[eid];
    srcP[p] = ei[NEDGE+eid];
  }
}

__global__ void k_init_h(const float* __restrict__ x, const float* __restrict__ w,
                         const float* __restrict__ b, float* __restrict__ h){
  int t = blockIdx.x*256 + threadIdx.x;
  if(t>=NH) return;
  int i=t>>6, j=t&63;
  float v = x[2*i]*w[j] + x[2*i+1]*w[64+j] + b[j];
  h[t] = fmaxf(v, 0.0f);
}

__global__ void k_init_e(const float* __restrict__ ea, const int* __restrict__ eidP,
                         const float* __restrict__ w, const float* __restrict__ b,
                         us* __restrict__ e){
  int t = blockIdx.x*256 + threadIdx.x;      // pair index
  if(t >= NE/2) return;
  int p = t>>5;          // slot
  int j = (t&31)<<1;
  float a = ea[eidP[p]];
  float v0 = fmaxf(a*w[j]   + b[j],   0.f);
  float v1 = fmaxf(a*w[j+1] + b[j+1], 0.f);
  unsigned int pk = (unsigned int)f2bf(v0) | ((unsigned int)f2bf(v1)<<16);
  *reinterpret_cast<unsigned int*>(&e[2*t]) = pk;
}

// ------------------------------------------------------------ tile helpers
__device__ __forceinline__ void tile_gemm(const float (&At)[64][68], const float (&Ws)[64][68],
                                          int r0, int c0, float (&acc)[4][4]){
  #pragma unroll 4
  for(int k=0;k<64;++k){
    const float4 a = *reinterpret_cast<const float4*>(&At[k][r0]);
    const float4 b = *reinterpret_cast<const float4*>(&Ws[k][c0]);
    const float av[4]={a.x,a.y,a.z,a.w};
    const float bv[4]={b.x,b.y,b.z,b.w};
    #pragma unroll
    for(int ri=0;ri<4;++ri)
      #pragma unroll
      for(int ci=0;ci<4;++ci)
        acc[ri][ci] = fmaf(av[ri], bv[ci], acc[ri][ci]);
  }
}

// GEMM with f16 weight LDS tile (k_edge_A)
__device__ __forceinline__ void tile_gemm_hW(const float (&At)[64][68], const us (&Wh)[64][68],
                                             int r0, int c0, float (&acc)[4][4]){
  #pragma unroll 4
  for(int k=0;k<64;++k){
    const float4 a = *reinterpret_cast<const float4*>(&At[k][r0]);
    const ushort4 b = *reinterpret_cast<const ushort4*>(&Wh[k][c0]);
    const float av[4]={a.x,a.y,a.z,a.w};
    const float bv[4]={hf2f(b.x),hf2f(b.y),hf2f(b.z),hf2f(b.w)};
    #pragma unroll
    for(int ri=0;ri<4;++ri)
      #pragma unroll
      for(int ci=0;ci<4;++ci)
        acc[ri][ci] = fmaf(av[ri], bv[ci], acc[ri][ci]);
  }
}

__device__ __forceinline__ void stage_At_f32(float (&At)[64][68], const float* __restrict__ src,
                                             int row0, int rowmax, int tid){
  for(int it=0; it<4; ++it){
    int idx = tid + it*256;
    int r = idx>>4, c4=(idx&15)<<2;
    int gr = row0 + r;
    float4 v = make_float4(0.f,0.f,0.f,0.f);
    if(gr < rowmax) v = *reinterpret_cast<const float4*>(&src[(size_t)gr*64 + c4]);
    At[c4+0][r]=v.x; At[c4+1][r]=v.y; At[c4+2][r]=v.z; At[c4+3][r]=v.w;
  }
}

__device__ __forceinline__ void stage_At_bf16(float (&At)[64][68], const us* __restrict__ src,
                                              int row0, int tid){
  #pragma unroll
  for(int it=0; it<2; ++it){
    int idx = tid + it*256;          // 0..511
    int r = idx>>3, c8 = (idx&7)<<3;
    int gr = row0 + r;
    const short8v v = *reinterpret_cast<const short8v*>(&src[(size_t)gr*64 + c8]);
    #pragma unroll
    for(int j=0;j<8;++j) At[c8+j][r] = bf2f((us)v[j]);
  }
}

__device__ __forceinline__ void stage_W(float (&Ws)[64][68], const float* __restrict__ W, int tid){
  for(int it=0; it<4; ++it){
    int idx = tid + it*256;
    int k = idx>>4, c4=(idx&15)<<2;
    *reinterpret_cast<float4*>(&Ws[k][c4]) = *reinterpret_cast<const float4*>(&W[k*64+c4]);
  }
}

// f32 global weights -> f16 LDS (k_edge_A)
__device__ __forceinline__ void stage_Wh(us (&Wh)[64][68], const float* __restrict__ W, int tid){
  for(int it=0; it<4; ++it){
    int idx = tid + it*256;
    int k = idx>>4, c4=(idx&15)<<2;
    const float4 w = *reinterpret_cast<const float4*>(&W[k*64+c4]);
    ushort4 o;
    o.x=f2hf(w.x); o.y=f2hf(w.y); o.z=f2hf(w.z); o.w=f2hf(w.w);
    *reinterpret_cast<ushort4*>(&Wh[k][c4]) = o;
  }
}

// ---------------------------------------------------------- node GEMMs
__device__ __forceinline__ void node_one_mat_f32(float (&At)[64][68], float (&Ws)[64][68],
    const float* __restrict__ W, const float* __restrict__ B, float* __restrict__ O,
    int row0, int tid){
  __syncthreads();
  stage_W(Ws, W, tid);
  __syncthreads();
  const int tx=tid&15, ty=tid>>4, r0=tx<<2, c0=ty<<2;
  float acc[4][4]={{0.f}};
  tile_gemm(At, Ws, r0, c0, acc);
  const float4 b4 = *reinterpret_cast<const float4*>(&B[c0]);
  const float bb[4]={b4.x,b4.y,b4.z,b4.w};
  #pragma unroll
  for(int ri=0;ri<4;++ri){
    int gr = row0 + r0 + ri;
    if(gr < NNODE){
      float4 o = make_float4(acc[ri][0]+bb[0], acc[ri][1]+bb[1],
                             acc[ri][2]+bb[2], acc[ri][3]+bb[3]);
      *reinterpret_cast<float4*>(&O[(size_t)gr*64 + c0]) = o;
    }
  }
}

__device__ __forceinline__ void node_one_mat_f16(float (&At)[64][68], float (&Ws)[64][68],
    const float* __restrict__ W, const float* __restrict__ B, us* __restrict__ O,
    int row0, int tid){
  __syncthreads();
  stage_W(Ws, W, tid);
  __syncthreads();
  const int tx=tid&15, ty=tid>>4, r0=tx<<2, c0=ty<<2;
  float acc[4][4]={{0.f}};
  tile_gemm(At, Ws, r0, c0, acc);
  const float4 b4 = *reinterpret_cast<const float4*>(&B[c0]);
  const float bb[4]={b4.x,b4.y,b4.z,b4.w};
  #pragma unroll
  for(int ri=0;ri<4;++ri){
    int gr = row0 + r0 + ri;
    if(gr < NNODE){
      unsigned int p0 = (unsigned int)f2hf(acc[ri][0]+bb[0]) | ((unsigned int)f2hf(acc[ri][1]+bb[1])<<16);
      unsigned int p1 = (unsigned int)f2hf(acc[ri][2]+bb[2]) | ((unsigned int)f2hf(acc[ri][3]+bb[3])<<16);
      *reinterpret_cast<uint2*>(&O[(size_t)gr*64 + c0]) = make_uint2(p0,p1);
    }
  }
}

__global__ __launch_bounds__(256) void k_node_gemm(
    const float* __restrict__ h,
    const float* __restrict__ Uw, const float* __restrict__ Ub,
    const float* __restrict__ Vw, const float* __restrict__ Vb,
    const float* __restrict__ Bw, const float* __restrict__ Bb,
    const float* __restrict__ Cw, const float* __restrict__ Cb,
    float* __restrict__ Uh, us* __restrict__ Vh,
    us* __restrict__ Bh, us* __restrict__ Ch)
{
  __shared__ float At[64][68];
  __shared__ float Ws[64][68];
  const int tid = threadIdx.x;
  const int row0 = blockIdx.x*64;
  stage_At_f32(At, h, row0, NNODE, tid);
  node_one_mat_f32(At, Ws, Uw, Ub, Uh, row0, tid);
  node_one_mat_f16(At, Ws, Vw, Vb, Vh, row0, tid);
  node_one_mat_f16(At, Ws, Bw, Bb, Bh, row0, tid);
  node_one_mat_f16(At, Ws, Cw, Cb, Ch, row0, tid);
}

// ---------------------------------------------------------- edge pass A
// f16 weight tile (26.6 KB LDS -> 6 blocks/CU); gathers issued before GEMM.
__global__ __launch_bounds__(256) void k_edge_A(
    const us* __restrict__ e,
    const float* __restrict__ Aw, const float* __restrict__ Ab,
    const us* __restrict__ Bh, const us* __restrict__ Ch,
    const int* __restrict__ dstP, const int* __restrict__ srcP,
    us* __restrict__ t16, float* __restrict__ buckets)
{
  __shared__ float At[64][68];   // 17408 B
  __shared__ us    Wh[64][68];   //  8704 B
  __shared__ float red[128];     //   512 B
  const int tid=threadIdx.x;
  const int row0 = blockIdx.x*64;
  if(tid<128) red[tid]=0.f;
  const int tx=tid&15, ty=tid>>4, r0=tx<<2, c0=ty<<2;
  // index loads: independent of LDS, issue before barrier
  int dstI[4], srcI[4];
  #pragma unroll
  for(int ri=0;ri<4;++ri){
    dstI[ri]=dstP[row0+r0+ri];
    srcI[ri]=srcP[row0+r0+ri];
  }
  stage_At_bf16(At, e, row0, tid);
  stage_Wh(Wh, Aw, tid);
  __syncthreads();
  // gathers in flight under the GEMM
  uint2 bh2[4], ch2[4];
  #pragma unroll
  for(int ri=0;ri<4;++ri){
    bh2[ri] = *reinterpret_cast<const uint2*>(&Bh[(size_t)dstI[ri]*64 + c0]);
    ch2[ri] = *reinterpret_cast<const uint2*>(&Ch[(size_t)srcI[ri]*64 + c0]);
  }
  float acc[4][4]={{0.f}};
  tile_gemm_hW(At, Wh, r0, c0, acc);

  const float4 ab4 = *reinterpret_cast<const float4*>(&Ab[c0]);
  const float ab[4]={ab4.x,ab4.y,ab4.z,ab4.w};

  float s1[4]={0.f,0.f,0.f,0.f}, s2[4]={0.f,0.f,0.f,0.f};
  #pragma unroll
  for(int ri=0;ri<4;++ri){
    const float bh[4]={hf2f((us)(bh2[ri].x&0xffff)), hf2f((us)(bh2[ri].x>>16)),
                       hf2f((us)(bh2[ri].y&0xffff)), hf2f((us)(bh2[ri].y>>16))};
    const float ch[4]={hf2f((us)(ch2[ri].x&0xffff)), hf2f((us)(ch2[ri].x>>16)),
                       hf2f((us)(ch2[ri].y&0xffff)), hf2f((us)(ch2[ri].y>>16))};
    float tv[4];
    #pragma unroll
    for(int ci=0;ci<4;++ci){
      float t = acc[ri][ci] + ab[ci] + bh[ci] + ch[ci];
      tv[ci]=t;
      s1[ci]+=t; s2[ci]+=t*t;
    }
    unsigned int p0 = (unsigned int)f2hf(tv[0]) | ((unsigned int)f2hf(tv[1])<<16);
    unsigned int p1 = (unsigned int)f2hf(tv[2]) | ((unsigned int)f2hf(tv[3])<<16);
    *reinterpret_cast<uint2*>(&t16[(size_t)(row0+r0+ri)*64 + c0]) = make_uint2(p0,p1);
  }
  #pragma unroll
  for(int ci=0;ci<4;++ci){
    atomicAdd(&red[c0+ci],    s1[ci]);
    atomicAdd(&red[64+c0+ci], s2[ci]);
  }
  __syncthreads();
  float* bk = buckets + (size_t)(blockIdx.x & (NBUCKET-1))*256;
  if(tid<128) atomicAdd(&bk[tid], red[tid]);
}

// ---------------------------------------------------------- CSR aggregation + h-BN stats
__global__ __launch_bounds__(256) void k_agg(
    const us* __restrict__ e,
    const us* __restrict__ Vh,
    const int* __restrict__ srcP,
    const int* __restrict__ row_ptr,
    const float* __restrict__ invc,
    float* __restrict__ Uh, float* __restrict__ buckets)
{
  __shared__ float red[128];
  const int tid=threadIdx.x;
  if(tid<128) red[tid]=0.f;
  __syncthreads();
  const int lane = tid&63;
  const int node = blockIdx.x*4 + (tid>>6);   // 4 waves/block
  const int beg = row_ptr[node];
  const int end = row_ptr[node+1];
  float acc = 0.f;
  int p = beg;
  for(; p+4<=end; p+=4){
    int s0=srcP[p], s1i=srcP[p+1], s2i=srcP[p+2], s3=srcP[p+3];
    float v0=hf2f(Vh[(size_t)s0*64 + lane]);
    float v1=hf2f(Vh[(size_t)s1i*64 + lane]);
    float v2=hf2f(Vh[(size_t)s2i*64 + lane]);
    float v3=hf2f(Vh[(size_t)s3*64 + lane]);
    float e0=bf2f(e[(size_t)(p+0)*64 + lane]);
    float e1=bf2f(e[(size_t)(p+1)*64 + lane]);
    float e2=bf2f(e[(size_t)(p+2)*64 + lane]);
    float e3=bf2f(e[(size_t)(p+3)*64 + lane]);
    acc = fmaf(sigf(e0), v0, acc);
    acc = fmaf(sigf(e1), v1, acc);
    acc = fmaf(sigf(e2), v2, acc);
    acc = fmaf(sigf(e3), v3, acc);
  }
  for(; p<end; ++p){
    int src = srcP[p];
    float g = sigf(bf2f(e[(size_t)p*64 + lane]));
    acc = fmaf(g, hf2f(Vh[(size_t)src*64 + lane]), acc);
  }
  size_t o = (size_t)node*64 + lane;
  float val = Uh[o] + acc*invc[node];
  Uh[o] = val;
  atomicAdd(&red[lane], val);
  atomicAdd(&red[64+lane], val*val);
  __syncthreads();
  float* bk = buckets + (size_t)(blockIdx.x & (NBUCKET-1))*256;
  if(tid<128) atomicAdd(&bk[128+tid], red[tid]);
}

// ---------------------------------------------------------- bucket reduce
__global__ void k_redstats(const float* __restrict__ buckets, float* __restrict__ stats){
  const int tid = threadIdx.x;
  float s = 0.f;
  for(int b=0;b<NBUCKET;++b) s += buckets[(size_t)b*256 + tid];
  stats[tid] = s;
}

__global__ void k_node_finB(const float* __restrict__ th, float* __restrict__ h,
                            const float* __restrict__ stats,
                            const float* __restrict__ hg, const float* __restrict__ hb){
  int t = blockIdx.x*256 + threadIdx.x;
  if(t>=NH) return;
  int j=t&63;
  const float invN = 1.0f/(float)NNODE;
  float mean = stats[128+j]*invN;
  float var  = stats[192+j]*invN - mean*mean;
  float rstd = rsqrtf(var + BN_EPS);
  float v = (th[t]-mean)*rstd*hg[j] + hb[j];
  h[t] += fmaxf(v, 0.0f);
}

// ---------------------------------------------------------- edge BN finalize
__global__ __launch_bounds__(256) void k_ebn(
    const us* __restrict__ t16,
    const float* __restrict__ stats,
    const float* __restrict__ eg, const float* __restrict__ eb,
    us* __restrict__ e)
{
  __shared__ float a_s[64], b_s[64];
  const int tid=threadIdx.x;
  if(tid<64){
    const float invE = 1.0f/(float)NEDGE;
    float mean = stats[tid]*invE;
    float var  = stats[64+tid]*invE - mean*mean;
    float rstd = rsqrtf(var + BN_EPS);
    float a = rstd*eg[tid];
    a_s[tid]=a;
    b_s[tid]=eb[tid]-mean*a;
  }
  __syncthreads();
  size_t idx = (size_t)blockIdx.x*256 + tid;   // NE/8 threads
  int j0 = ((int)idx&7)<<3;
  const short8v tv = *reinterpret_cast<const short8v*>(&t16[idx*8]);
  const short8v ev = *reinterpret_cast<const short8v*>(&e[idx*8]);
  short8v ov;
  #pragma unroll
  for(int j=0;j<8;++j){
    float tt = hf2f((us)tv[j]);
    float v  = tt*a_s[j0+j] + b_s[j0+j];
    float o  = bf2f((us)ev[j]) + fmaxf(v, 0.0f);
    ov[j] = (short)f2bf(o);
  }
  *reinterpret_cast<short8v*>(&e[idx*8]) = ov;
}

// ---------------------------------------------------------- final MLP (fused)
__global__ __launch_bounds__(256) void k_mlp(
    const us* __restrict__ e,
    const int* __restrict__ eidP,
    const float* __restrict__ f1w, const float* __restrict__ f1b,
    const float* __restrict__ f2w, const float* __restrict__ f2b,
    const float* __restrict__ f3w, const float* __restrict__ f3b,
    float* __restrict__ out)
{
  __shared__ float At[64][68];
  __shared__ float Ws[64][68];
  __shared__ float ored[64];
  const int tid=threadIdx.x;
  const int row0 = blockIdx.x*64;
  if(tid<64) ored[tid]=0.f;
  stage_At_bf16(At, e, row0, tid);
  stage_W(Ws, f1w, tid);
  __syncthreads();
  const int tx=tid&15, ty=tid>>4, r0=tx<<2, c0=ty<<2;
  float acc[4][4]={{0.f}};
  tile_gemm(At, Ws, r0, c0, acc);
  const float4 b14 = *reinterpret_cast<const float4*>(&f1b[c0]);
  const float b1[4]={b14.x,b14.y,b14.z,b14.w};
  float z1[4][4];
  #pragma unroll
  for(int ri=0;ri<4;++ri)
    #pragma unroll
    for(int ci=0;ci<4;++ci){
      float v = acc[ri][ci]+b1[ci];
      z1[ri][ci] = v*sigf(v);
    }
  __syncthreads();
  #pragma unroll
  for(int ri=0;ri<4;++ri)
    #pragma unroll
    for(int ci=0;ci<4;++ci)
      At[c0+ci][r0+ri] = z1[ri][ci];
  stage_W(Ws, f2w, tid);
  __syncthreads();
  float acc2[4][4]={{0.f}};
  tile_gemm(At, Ws, r0, c0, acc2);
  const float4 b24 = *reinterpret_cast<const float4*>(&f2b[c0]);
  const float b2[4]={b24.x,b24.y,b24.z,b24.w};
  const float4 w34 = *reinterpret_cast<const float4*>(&f3w[c0]);
  const float w3[4]={w34.x,w34.y,w34.z,w34.w};
  float part[4]={0.f,0.f,0.f,0.f};
  #pragma unroll
  for(int ri=0;ri<4;++ri)
    #pragma unroll
    for(int ci=0;ci<4;++ci){
      float v = acc2[ri][ci]+b2[ci];
      float z = v*sigf(v);
      part[ri] += z*w3[ci];
    }
  #pragma unroll
  for(int ri=0;ri<4;++ri) atomicAdd(&ored[r0+ri], part[ri]);
  __syncthreads();
  if(tid<64) out[eidP[row0+tid]] = sigf(ored[tid] + f3b[0]);
}

// ---------------------------------------------------------------- launch
extern "C" void kernel_launch(void* const* d_in, const int* in_sizes, int n_in,
                              void* d_out, int out_size, void* d_ws, size_t ws_size,
                              hipStream_t stream){
  const float* x    = (const float*)d_in[0];
  const float* ea   = (const float*)d_in[1];
  const int*   ei   = (const int*)  d_in[2];
  const float* hp_w = (const float*)d_in[3];
  const float* hp_b = (const float*)d_in[4];
  const float* ep_w = (const float*)d_in[5];
  const float* ep_b = (const float*)d_in[6];
  const float* Uw   = (const float*)d_in[7];
  const float* Ub   = (const float*)d_in[8];
  const float* Vw   = (const float*)d_in[9];
  const float* Vb   = (const float*)d_in[10];
  const float* Aw   = (const float*)d_in[11];
  const float* Ab   = (const float*)d_in[12];
  const float* Bw   = (const float*)d_in[13];
  const float* Bb   = (const float*)d_in[14];
  const float* Cw   = (const float*)d_in[15];
  const float* Cb   = (const float*)d_in[16];
  const float* hg   = (const float*)d_in[17];
  const float* hb   = (const float*)d_in[18];
  const float* eg   = (const float*)d_in[19];
  const float* eb   = (const float*)d_in[20];
  const float* f1w  = (const float*)d_in[21];
  const float* f1b  = (const float*)d_in[22];
  const float* f2w  = (const float*)d_in[23];
  const float* f2b  = (const float*)d_in[24];
  const float* f3w  = (const float*)d_in[25];
  const float* f3b  = (const float*)d_in[26];

  // ws: e(bf16) | t(f16) | h(f32) | Uh(f32) | stats | buckets | Vh/Bh/Ch(f16) | int arrays
  char* base = (char*)d_ws;
  us* e    = (us*)base;                               // 102.4 MB
  us* t16  = (us*)(base + (size_t)NE*2);              // 102.4 MB
  float* h  = (float*)(base + 2ull*NE*2);             // 12.8 MB
  float* Uh = h + (size_t)NH;                         // 12.8 MB
  float* stats = Uh + (size_t)NH;                     // 1 KB
  float* buckets = stats + 256;                       // 256 KB (256x256)
  us* Vh = (us*)(buckets + NBUCKET*256);              // 6.4 MB
  us* Bh = Vh + (size_t)NH;                           // 6.4 MB
  us* Ch = Bh + (size_t)NH;                           // 6.4 MB
  int* cnt     = (int*)(Ch + (size_t)NH);             // 0.2 MB
  float* invc  = (float*)(cnt + NNODE);
  int* row_ptr = (int*)(invc + NNODE);
  int* cursor  = row_ptr + NNODE + 1;
  int* eidP    = cursor + NNODE;                      // 3.2 MB
  int* dstP    = eidP + NEDGE;                        // 3.2 MB
  int* srcP    = dstP + NEDGE;                        // 3.2 MB
  // total ≈ 260.3 MB

  dim3 blk(256);
  k_zero_i<<<dim3((NNODE+255)/256), blk, 0, stream>>>(cnt, NNODE);
  k_count <<<dim3((NEDGE+255)/256), blk, 0, stream>>>(ei, cnt);
  k_inv   <<<dim3((NNODE+255)/256), blk, 0, stream>>>(cnt, invc);
  k_scan  <<<dim3(1), blk, 0, stream>>>(cnt, row_ptr, cursor);
  k_fill  <<<dim3((NEDGE+255)/256), blk, 0, stream>>>(ei, cursor, eidP);
  k_perm  <<<dim3((NEDGE+255)/256), blk, 0, stream>>>(ei, eidP, dstP, srcP);
  k_init_h<<<dim3((NH+255)/256), blk, 0, stream>>>(x, hp_w, hp_b, h);
  k_init_e<<<dim3((NE/2+255)/256), blk, 0, stream>>>(ea, eidP, ep_w, ep_b, e);

  for(int l=0;l<NLAYER;++l){
    k_zero_f<<<dim3(NBUCKET*256/256), blk, 0, stream>>>(buckets, NBUCKET*256);
    k_node_gemm<<<dim3((NNODE+63)/64), blk, 0, stream>>>(h,
        Uw+l*4096, Ub+l*64, Vw+l*4096, Vb+l*64,
        Bw+l*4096, Bb+l*64, Cw+l*4096, Cb+l*64,
        Uh, Vh, Bh, Ch);
    k_edge_A<<<dim3(NEDGE/64), blk, 0, stream>>>(e, Aw+l*4096, Ab+l*64,
        Bh, Ch, dstP, srcP, t16, buckets);
    k_agg<<<dim3(NNODE/4), blk, 0, stream>>>(e, Vh, srcP, row_ptr,
        invc, Uh, buckets);
    k_redstats<<<dim3(1), blk, 0, stream>>>(buckets, stats);
    k_node_finB<<<dim3(NH/256), blk, 0, stream>>>(Uh, h, stats, hg+l*64, hb+l*64);
    k_ebn<<<dim3(NE/8/256), blk, 0, stream>>>(t16, stats, eg+l*64, eb+l*64, e);
  }
  k_mlp<<<dim3(NEDGE/64), blk, 0, stream>>>(e, eidP, f1w, f1b, f2w, f2b,
                                            f3w, f3b, (float*)d_out);
}

// Round 16
// 2015.543 us; speedup vs baseline: 3.5701x; 1.1633x over previous
//
#include <hip/hip_runtime.h>

#define NNODE 50000
#define NEDGE 800000
#define NLAYER 4
#define BN_EPS 1e-5f

#define NH (NNODE*64)   // 3,200,000
#define NE (NEDGE*64)   // 51,200,000
#define NBUCKET 256
#define NGB 782         // node-gemm row blocks = ceil(50000/64)

typedef __attribute__((ext_vector_type(8))) short short8v;
typedef unsigned short us;

__device__ __forceinline__ float sigf(float x){ return 1.0f/(1.0f+__expf(-x)); }

__device__ __forceinline__ float bf2f(us u){
  union { unsigned int i; float f; } c; c.i = ((unsigned int)u)<<16; return c.f;
}
__device__ __forceinline__ us f2bf(float f){
  union { float f; unsigned int i; } c; c.f = f;
  unsigned int r = c.i + 0x7FFFu + ((c.i>>16)&1u);   // RNE
  return (us)(r>>16);
}
__device__ __forceinline__ float hf2f(us u){
  union { us u; _Float16 h; } c; c.u=u; return (float)c.h;
}
__device__ __forceinline__ us f2hf(float f){
  union { us u; _Float16 h; } c; c.h=(_Float16)f; return c.u;
}

// ---------------------------------------------------------------- utility
__global__ void k_zero_i(int* __restrict__ p, int n){
  int i = blockIdx.x*256 + threadIdx.x;
  if(i<n) p[i]=0;
}
__global__ void k_zero_f(float* __restrict__ p, int n){
  int i = blockIdx.x*256 + threadIdx.x;
  if(i<n) p[i]=0.f;
}
__global__ void k_count(const int* __restrict__ ei, int* __restrict__ cnt){
  int i = blockIdx.x*256 + threadIdx.x;
  if(i<NEDGE) atomicAdd(&cnt[ei[i]], 1);   // ei[0][i] = dst
}
__global__ void k_inv(const int* __restrict__ cnt, float* __restrict__ invc){
  int i = blockIdx.x*256 + threadIdx.x;
  if(i<NNODE){ int c=cnt[i]; invc[i] = 1.0f/(float)(c<1?1:c); }
}

__global__ void k_scan(const int* __restrict__ cnt, int* __restrict__ row_ptr,
                       int* __restrict__ cursor){
  __shared__ int buf[256];
  __shared__ int carry;
  const int tid = threadIdx.x;
  if(tid==0) carry=0;
  __syncthreads();
  for(int base=0; base<NNODE; base+=256){
    int i = base+tid;
    int v = (i<NNODE)? cnt[i] : 0;
    buf[tid]=v; __syncthreads();
    #pragma unroll
    for(int off=1; off<256; off<<=1){
      int t = (tid>=off)? buf[tid-off] : 0;
      __syncthreads();
      buf[tid]+=t;
      __syncthreads();
    }
    int excl = carry + buf[tid]-v;
    if(i<NNODE){ row_ptr[i]=excl; cursor[i]=excl; }
    __syncthreads();
    if(tid==0) carry += buf[255];
    __syncthreads();
  }
  if(tid==0) row_ptr[NNODE]=carry;
}

__global__ void k_fill(const int* __restrict__ ei, int* __restrict__ cursor,
                       int* __restrict__ eidP){
  int i = blockIdx.x*256 + threadIdx.x;
  if(i<NEDGE){
    int pos = atomicAdd(&cursor[ei[i]], 1);
    eidP[pos] = i;
  }
}

__global__ void k_perm(const int* __restrict__ ei, const int* __restrict__ eidP,
                       int* __restrict__ dstP, int* __restrict__ srcP){
  int p = blockIdx.x*256 + threadIdx.x;
  if(p<NEDGE){
    int eid = eidP[p];
    dstP[p] = ei[eid];
    srcP[p] = ei[NEDGE+eid];
  }
}

__global__ void k_init_h(const float* __restrict__ x, const float* __restrict__ w,
                         const float* __restrict__ b, float* __restrict__ h){
  int t = blockIdx.x*256 + threadIdx.x;
  if(t>=NH) return;
  int i=t>>6, j=t&63;
  float v = x[2*i]*w[j] + x[2*i+1]*w[64+j] + b[j];
  h[t] = fmaxf(v, 0.0f);
}

__global__ void k_init_e(const float* __restrict__ ea, const int* __restrict__ eidP,
                         const float* __restrict__ w, const float* __restrict__ b,
                         us* __restrict__ e){
  int t = blockIdx.x*256 + threadIdx.x;      // pair index
  if(t >= NE/2) return;
  int p = t>>5;          // slot
  int j = (t&31)<<1;
  float a = ea[eidP[p]];
  float v0 = fmaxf(a*w[j]   + b[j],   0.f);
  float v1 = fmaxf(a*w[j+1] + b[j+1], 0.f);
  unsigned int pk = (unsigned int)f2bf(v0) | ((unsigned int)f2bf(v1)<<16);
  *reinterpret_cast<unsigned int*>(&e[2*t]) = pk;
}

// ------------------------------------------------------------ tile helpers
__device__ __forceinline__ void tile_gemm(const float (&At)[64][68], const float (&Ws)[64][68],
                                          int r0, int c0, float (&acc)[4][4]){
  #pragma unroll 4
  for(int k=0;k<64;++k){
    const float4 a = *reinterpret_cast<const float4*>(&At[k][r0]);
    const float4 b = *reinterpret_cast<const float4*>(&Ws[k][c0]);
    const float av[4]={a.x,a.y,a.z,a.w};
    const float bv[4]={b.x,b.y,b.z,b.w};
    #pragma unroll
    for(int ri=0;ri<4;++ri)
      #pragma unroll
      for(int ci=0;ci<4;++ci)
        acc[ri][ci] = fmaf(av[ri], bv[ci], acc[ri][ci]);
  }
}

__device__ __forceinline__ void stage_At_f32(float (&At)[64][68], const float* __restrict__ src,
                                             int row0, int rowmax, int tid){
  for(int it=0; it<4; ++it){
    int idx = tid + it*256;
    int r = idx>>4, c4=(idx&15)<<2;
    int gr = row0 + r;
    float4 v = make_float4(0.f,0.f,0.f,0.f);
    if(gr < rowmax) v = *reinterpret_cast<const float4*>(&src[(size_t)gr*64 + c4]);
    At[c4+0][r]=v.x; At[c4+1][r]=v.y; At[c4+2][r]=v.z; At[c4+3][r]=v.w;
  }
}

__device__ __forceinline__ void stage_At_bf16(float (&At)[64][68], const us* __restrict__ src,
                                              int row0, int tid){
  #pragma unroll
  for(int it=0; it<2; ++it){
    int idx = tid + it*256;          // 0..511
    int r = idx>>3, c8 = (idx&7)<<3;
    int gr = row0 + r;
    const short8v v = *reinterpret_cast<const short8v*>(&src[(size_t)gr*64 + c8]);
    #pragma unroll
    for(int j=0;j<8;++j) At[c8+j][r] = bf2f((us)v[j]);
  }
}

__device__ __forceinline__ void stage_W(float (&Ws)[64][68], const float* __restrict__ W, int tid){
  for(int it=0; it<4; ++it){
    int idx = tid + it*256;
    int k = idx>>4, c4=(idx&15)<<2;
    *reinterpret_cast<float4*>(&Ws[k][c4]) = *reinterpret_cast<const float4*>(&W[k*64+c4]);
  }
}

// f32 global weights -> f16 LDS (k_edge_A)
__device__ __forceinline__ void stage_Wh(us (&Wh)[64][68], const float* __restrict__ W, int tid){
  for(int it=0; it<4; ++it){
    int idx = tid + it*256;
    int k = idx>>4, c4=(idx&15)<<2;
    const float4 w = *reinterpret_cast<const float4*>(&W[k*64+c4]);
    ushort4 o;
    o.x=f2hf(w.x); o.y=f2hf(w.y); o.z=f2hf(w.z); o.w=f2hf(w.w);
    *reinterpret_cast<ushort4*>(&Wh[k][c4]) = o;
  }
}

// ---------------------------------------------------------- node GEMMs
// one 64x64 matrix per block: mat 0 -> Uh (f32); 1,2,3 -> Vh,Bh,Ch (f16)
__global__ __launch_bounds__(256) void k_node_gemm(
    const float* __restrict__ h,
    const float* __restrict__ Uw, const float* __restrict__ Ub,
    const float* __restrict__ Vw, const float* __restrict__ Vb,
    const float* __restrict__ Bw, const float* __restrict__ Bb,
    const float* __restrict__ Cw, const float* __restrict__ Cb,
    float* __restrict__ Uh, us* __restrict__ Vh,
    us* __restrict__ Bh, us* __restrict__ Ch)
{
  __shared__ float At[64][68];
  __shared__ float Ws[64][68];
  const int tid = threadIdx.x;
  const int bid = blockIdx.x;
  const int mat = bid / NGB;          // 0..3
  const int row0 = (bid % NGB)*64;
  const float* W = (mat==0)? Uw : (mat==1)? Vw : (mat==2)? Bw : Cw;
  const float* B = (mat==0)? Ub : (mat==1)? Vb : (mat==2)? Bb : Cb;
  stage_At_f32(At, h, row0, NNODE, tid);
  stage_W(Ws, W, tid);
  __syncthreads();
  const int tx=tid&15, ty=tid>>4, r0=tx<<2, c0=ty<<2;
  float acc[4][4]={{0.f}};
  tile_gemm(At, Ws, r0, c0, acc);
  const float4 b4 = *reinterpret_cast<const float4*>(&B[c0]);
  const float bb[4]={b4.x,b4.y,b4.z,b4.w};
  if(mat==0){
    #pragma unroll
    for(int ri=0;ri<4;++ri){
      int gr = row0 + r0 + ri;
      if(gr < NNODE){
        float4 o = make_float4(acc[ri][0]+bb[0], acc[ri][1]+bb[1],
                               acc[ri][2]+bb[2], acc[ri][3]+bb[3]);
        *reinterpret_cast<float4*>(&Uh[(size_t)gr*64 + c0]) = o;
      }
    }
  } else {
    us* O = (mat==1)? Vh : (mat==2)? Bh : Ch;
    #pragma unroll
    for(int ri=0;ri<4;++ri){
      int gr = row0 + r0 + ri;
      if(gr < NNODE){
        unsigned int p0 = (unsigned int)f2hf(acc[ri][0]+bb[0]) | ((unsigned int)f2hf(acc[ri][1]+bb[1])<<16);
        unsigned int p1 = (unsigned int)f2hf(acc[ri][2]+bb[2]) | ((unsigned int)f2hf(acc[ri][3]+bb[3])<<16);
        *reinterpret_cast<uint2*>(&O[(size_t)gr*64 + c0]) = make_uint2(p0,p1);
      }
    }
  }
}

// ---------------------------------------------------------- edge pass A
// 128-edge tiles: 8x4 micro-tile per thread; raw-bf16 e tile + f16 weight tile
// LDS = 17408 + 8704 + 512 = 26.6 KB -> 6 blocks/CU
__global__ __launch_bounds__(256) void k_edge_A(
    const us* __restrict__ e,
    const float* __restrict__ Aw, const float* __restrict__ Ab,
    const us* __restrict__ Bh, const us* __restrict__ Ch,
    const int* __restrict__ dstP, const int* __restrict__ srcP,
    us* __restrict__ t16, float* __restrict__ buckets)
{
  __shared__ us    Ats[64][136];  // [k][row], raw bf16, 17408 B
  __shared__ us    Wh[64][68];    // f16 weights, 8704 B
  __shared__ float red[128];      // 512 B
  const int tid=threadIdx.x;
  const int row0 = blockIdx.x*128;
  if(tid<128) red[tid]=0.f;
  // stage e tile (128 rows x 64 cols, transposed, raw bf16)
  #pragma unroll
  for(int it=0; it<4; ++it){
    int idx = tid + it*256;          // 0..1023
    int r = idx>>3, c8 = (idx&7)<<3;
    const short8v v = *reinterpret_cast<const short8v*>(&e[(size_t)(row0+r)*64 + c8]);
    #pragma unroll
    for(int j=0;j<8;++j) Ats[c8+j][r] = (us)v[j];
  }
  stage_Wh(Wh, Aw, tid);
  __syncthreads();

  const int tx=tid&15, ty=tid>>4, r0=tx<<3, c0=ty<<2;
  float acc[8][4]={{0.f}};
  #pragma unroll 2
  for(int k=0;k<64;++k){
    const short8v a = *reinterpret_cast<const short8v*>(&Ats[k][r0]);
    const ushort4 b = *reinterpret_cast<const ushort4*>(&Wh[k][c0]);
    const float bv[4]={hf2f(b.x),hf2f(b.y),hf2f(b.z),hf2f(b.w)};
    #pragma unroll
    for(int ri=0;ri<8;++ri){
      const float av = bf2f((us)a[ri]);
      #pragma unroll
      for(int ci=0;ci<4;++ci)
        acc[ri][ci] = fmaf(av, bv[ci], acc[ri][ci]);
    }
  }

  const float4 ab4 = *reinterpret_cast<const float4*>(&Ab[c0]);
  const float ab[4]={ab4.x,ab4.y,ab4.z,ab4.w};

  float s1[4]={0.f,0.f,0.f,0.f}, s2[4]={0.f,0.f,0.f,0.f};
  #pragma unroll
  for(int ri=0;ri<8;++ri){
    const int slot = row0 + r0 + ri;
    const int dstI = dstP[slot];
    const int srcI = srcP[slot];
    const uint2 b2 = *reinterpret_cast<const uint2*>(&Bh[(size_t)dstI*64 + c0]);
    const uint2 c2 = *reinterpret_cast<const uint2*>(&Ch[(size_t)srcI*64 + c0]);
    const float bh[4]={hf2f((us)(b2.x&0xffff)), hf2f((us)(b2.x>>16)),
                       hf2f((us)(b2.y&0xffff)), hf2f((us)(b2.y>>16))};
    const float ch[4]={hf2f((us)(c2.x&0xffff)), hf2f((us)(c2.x>>16)),
                       hf2f((us)(c2.y&0xffff)), hf2f((us)(c2.y>>16))};
    float tv[4];
    #pragma unroll
    for(int ci=0;ci<4;++ci){
      float t = acc[ri][ci] + ab[ci] + bh[ci] + ch[ci];
      tv[ci]=t;
      s1[ci]+=t; s2[ci]+=t*t;
    }
    unsigned int p0 = (unsigned int)f2hf(tv[0]) | ((unsigned int)f2hf(tv[1])<<16);
    unsigned int p1 = (unsigned int)f2hf(tv[2]) | ((unsigned int)f2hf(tv[3])<<16);
    *reinterpret_cast<uint2*>(&t16[(size_t)slot*64 + c0]) = make_uint2(p0,p1);
  }
  #pragma unroll
  for(int ci=0;ci<4;++ci){
    atomicAdd(&red[c0+ci],    s1[ci]);
    atomicAdd(&red[64+c0+ci], s2[ci]);
  }
  __syncthreads();
  float* bk = buckets + (size_t)(blockIdx.x & (NBUCKET-1))*256;
  if(tid<128) atomicAdd(&bk[tid], red[tid]);
}

// ---------------------------------------------------------- CSR aggregation + h-BN stats
__global__ __launch_bounds__(256) void k_agg(
    const us* __restrict__ e,
    const us* __restrict__ Vh,
    const int* __restrict__ srcP,
    const int* __restrict__ row_ptr,
    const float* __restrict__ invc,
    float* __restrict__ Uh, float* __restrict__ buckets)
{
  __shared__ float red[128];
  const int tid=threadIdx.x;
  if(tid<128) red[tid]=0.f;
  __syncthreads();
  const int lane = tid&63;
  const int node = blockIdx.x*4 + (tid>>6);   // 4 waves/block
  const int beg = row_ptr[node];
  const int end = row_ptr[node+1];
  float acc = 0.f;
  int p = beg;
  for(; p+4<=end; p+=4){
    int s0=srcP[p], s1i=srcP[p+1], s2i=srcP[p+2], s3=srcP[p+3];
    float v0=hf2f(Vh[(size_t)s0*64 + lane]);
    float v1=hf2f(Vh[(size_t)s1i*64 + lane]);
    float v2=hf2f(Vh[(size_t)s2i*64 + lane]);
    float v3=hf2f(Vh[(size_t)s3*64 + lane]);
    float e0=bf2f(e[(size_t)(p+0)*64 + lane]);
    float e1=bf2f(e[(size_t)(p+1)*64 + lane]);
    float e2=bf2f(e[(size_t)(p+2)*64 + lane]);
    float e3=bf2f(e[(size_t)(p+3)*64 + lane]);
    acc = fmaf(sigf(e0), v0, acc);
    acc = fmaf(sigf(e1), v1, acc);
    acc = fmaf(sigf(e2), v2, acc);
    acc = fmaf(sigf(e3), v3, acc);
  }
  for(; p<end; ++p){
    int src = srcP[p];
    float g = sigf(bf2f(e[(size_t)p*64 + lane]));
    acc = fmaf(g, hf2f(Vh[(size_t)src*64 + lane]), acc);
  }
  size_t o = (size_t)node*64 + lane;
  float val = Uh[o] + acc*invc[node];
  Uh[o] = val;
  atomicAdd(&red[lane], val);
  atomicAdd(&red[64+lane], val*val);
  __syncthreads();
  float* bk = buckets + (size_t)(blockIdx.x & (NBUCKET-1))*256;
  if(tid<128) atomicAdd(&bk[128+tid], red[tid]);
}

// ---------------------------------------------------------- bucket reduce (+re-zero for next layer)
__global__ void k_redstats(float* __restrict__ buckets, float* __restrict__ stats){
  const int tid = threadIdx.x;
  float s = 0.f;
  for(int b=0;b<NBUCKET;++b){
    s += buckets[(size_t)b*256 + tid];
    buckets[(size_t)b*256 + tid] = 0.f;
  }
  stats[tid] = s;
}

__global__ void k_node_finB(const float* __restrict__ th, float* __restrict__ h,
                            const float* __restrict__ stats,
                            const float* __restrict__ hg, const float* __restrict__ hb){
  int t = blockIdx.x*256 + threadIdx.x;
  if(t>=NH) return;
  int j=t&63;
  const float invN = 1.0f/(float)NNODE;
  float mean = stats[128+j]*invN;
  float var  = stats[192+j]*invN - mean*mean;
  float rstd = rsqrtf(var + BN_EPS);
  float v = (th[t]-mean)*rstd*hg[j] + hb[j];
  h[t] += fmaxf(v, 0.0f);
}

// ---------------------------------------------------------- edge BN finalize
__global__ __launch_bounds__(256) void k_ebn(
    const us* __restrict__ t16,
    const float* __restrict__ stats,
    const float* __restrict__ eg, const float* __restrict__ eb,
    us* __restrict__ e)
{
  __shared__ float a_s[64], b_s[64];
  const int tid=threadIdx.x;
  if(tid<64){
    const float invE = 1.0f/(float)NEDGE;
    float mean = stats[tid]*invE;
    float var  = stats[64+tid]*invE - mean*mean;
    float rstd = rsqrtf(var + BN_EPS);
    float a = rstd*eg[tid];
    a_s[tid]=a;
    b_s[tid]=eb[tid]-mean*a;
  }
  __syncthreads();
  size_t idx = (size_t)blockIdx.x*256 + tid;   // NE/8 threads
  int j0 = ((int)idx&7)<<3;
  const short8v tv = *reinterpret_cast<const short8v*>(&t16[idx*8]);
  const short8v ev = *reinterpret_cast<const short8v*>(&e[idx*8]);
  short8v ov;
  #pragma unroll
  for(int j=0;j<8;++j){
    float tt = hf2f((us)tv[j]);
    float v  = tt*a_s[j0+j] + b_s[j0+j];
    float o  = bf2f((us)ev[j]) + fmaxf(v, 0.0f);
    ov[j] = (short)f2bf(o);
  }
  *reinterpret_cast<short8v*>(&e[idx*8]) = ov;
}

// ---------------------------------------------------------- final MLP (fused)
__global__ __launch_bounds__(256) void k_mlp(
    const us* __restrict__ e,
    const int* __restrict__ eidP,
    const float* __restrict__ f1w, const float* __restrict__ f1b,
    const float* __restrict__ f2w, const float* __restrict__ f2b,
    const float* __restrict__ f3w, const float* __restrict__ f3b,
    float* __restrict__ out)
{
  __shared__ float At[64][68];
  __shared__ float Ws[64][68];
  __shared__ float ored[64];
  const int tid=threadIdx.x;
  const int row0 = blockIdx.x*64;
  if(tid<64) ored[tid]=0.f;
  stage_At_bf16(At, e, row0, tid);
  stage_W(Ws, f1w, tid);
  __syncthreads();
  const int tx=tid&15, ty=tid>>4, r0=tx<<2, c0=ty<<2;
  float acc[4][4]={{0.f}};
  tile_gemm(At, Ws, r0, c0, acc);
  const float4 b14 = *reinterpret_cast<const float4*>(&f1b[c0]);
  const float b1[4]={b14.x,b14.y,b14.z,b14.w};
  float z1[4][4];
  #pragma unroll
  for(int ri=0;ri<4;++ri)
    #pragma unroll
    for(int ci=0;ci<4;++ci){
      float v = acc[ri][ci]+b1[ci];
      z1[ri][ci] = v*sigf(v);
    }
  __syncthreads();
  #pragma unroll
  for(int ri=0;ri<4;++ri)
    #pragma unroll
    for(int ci=0;ci<4;++ci)
      At[c0+ci][r0+ri] = z1[ri][ci];
  stage_W(Ws, f2w, tid);
  __syncthreads();
  float acc2[4][4]={{0.f}};
  tile_gemm(At, Ws, r0, c0, acc2);
  const float4 b24 = *reinterpret_cast<const float4*>(&f2b[c0]);
  const float b2[4]={b24.x,b24.y,b24.z,b24.w};
  const float4 w34 = *reinterpret_cast<const float4*>(&f3w[c0]);
  const float w3[4]={w34.x,w34.y,w34.z,w34.w};
  float part[4]={0.f,0.f,0.f,0.f};
  #pragma unroll
  for(int ri=0;ri<4;++ri)
    #pragma unroll
    for(int ci=0;ci<4;++ci){
      float v = acc2[ri][ci]+b2[ci];
      float z = v*sigf(v);
      part[ri] += z*w3[ci];
    }
  #pragma unroll
  for(int ri=0;ri<4;++ri) atomicAdd(&ored[r0+ri], part[ri]);
  __syncthreads();
  if(tid<64) out[eidP[row0+tid]] = sigf(ored[tid] + f3b[0]);
}

// ---------------------------------------------------------------- launch
extern "C" void kernel_launch(void* const* d_in, const int* in_sizes, int n_in,
                              void* d_out, int out_size, void* d_ws, size_t ws_size,
                              hipStream_t stream){
  const float* x    = (const float*)d_in[0];
  const float* ea   = (const float*)d_in[1];
  const int*   ei   = (const int*)  d_in[2];
  const float* hp_w = (const float*)d_in[3];
  const float* hp_b = (const float*)d_in[4];
  const float* ep_w = (const float*)d_in[5];
  const float* ep_b = (const float*)d_in[6];
  const float* Uw   = (const float*)d_in[7];
  const float* Ub   = (const float*)d_in[8];
  const float* Vw   = (const float*)d_in[9];
  const float* Vb   = (const float*)d_in[10];
  const float* Aw   = (const float*)d_in[11];
  const float* Ab   = (const float*)d_in[12];
  const float* Bw   = (const float*)d_in[13];
  const float* Bb   = (const float*)d_in[14];
  const float* Cw   = (const float*)d_in[15];
  const float* Cb   = (const float*)d_in[16];
  const float* hg   = (const float*)d_in[17];
  const float* hb   = (const float*)d_in[18];
  const float* eg   = (const float*)d_in[19];
  const float* eb   = (const float*)d_in[20];
  const float* f1w  = (const float*)d_in[21];
  const float* f1b  = (const float*)d_in[22];
  const float* f2w  = (const float*)d_in[23];
  const float* f2b  = (const float*)d_in[24];
  const float* f3w  = (const float*)d_in[25];
  const float* f3b  = (const float*)d_in[26];

  // ws: e(bf16) | t(f16) | h(f32) | Uh(f32) | stats | buckets | Vh/Bh/Ch(f16) | int arrays
  char* base = (char*)d_ws;
  us* e    = (us*)base;                               // 102.4 MB
  us* t16  = (us*)(base + (size_t)NE*2);              // 102.4 MB
  float* h  = (float*)(base + 2ull*NE*2);             // 12.8 MB
  float* Uh = h + (size_t)NH;                         // 12.8 MB
  float* stats = Uh + (size_t)NH;                     // 1 KB
  float* buckets = stats + 256;                       // 256 KB (256x256)
  us* Vh = (us*)(buckets + NBUCKET*256);              // 6.4 MB
  us* Bh = Vh + (size_t)NH;                           // 6.4 MB
  us* Ch = Bh + (size_t)NH;                           // 6.4 MB
  int* cnt     = (int*)(Ch + (size_t)NH);             // 0.2 MB
  float* invc  = (float*)(cnt + NNODE);
  int* row_ptr = (int*)(invc + NNODE);
  int* cursor  = row_ptr + NNODE + 1;
  int* eidP    = cursor + NNODE;                      // 3.2 MB
  int* dstP    = eidP + NEDGE;                        // 3.2 MB
  int* srcP    = dstP + NEDGE;                        // 3.2 MB
  // total ≈ 260.3 MB

  dim3 blk(256);
  k_zero_i<<<dim3((NNODE+255)/256), blk, 0, stream>>>(cnt, NNODE);
  k_count <<<dim3((NEDGE+255)/256), blk, 0, stream>>>(ei, cnt);
  k_inv   <<<dim3((NNODE+255)/256), blk, 0, stream>>>(cnt, invc);
  k_scan  <<<dim3(1), blk, 0, stream>>>(cnt, row_ptr, cursor);
  k_fill  <<<dim3((NEDGE+255)/256), blk, 0, stream>>>(ei, cursor, eidP);
  k_perm  <<<dim3((NEDGE+255)/256), blk, 0, stream>>>(ei, eidP, dstP, srcP);
  k_init_h<<<dim3((NH+255)/256), blk, 0, stream>>>(x, hp_w, hp_b, h);
  k_init_e<<<dim3((NE/2+255)/256), blk, 0, stream>>>(ea, eidP, ep_w, ep_b, e);
  k_zero_f<<<dim3(NBUCKET*256/256), blk, 0, stream>>>(buckets, NBUCKET*256);

  for(int l=0;l<NLAYER;++l){
    k_node_gemm<<<dim3(NGB*4), blk, 0, stream>>>(h,
        Uw+l*4096, Ub+l*64, Vw+l*4096, Vb+l*64,
        Bw+l*4096, Bb+l*64, Cw+l*4096, Cb+l*64,
        Uh, Vh, Bh, Ch);
    k_edge_A<<<dim3(NEDGE/128), blk, 0, stream>>>(e, Aw+l*4096, Ab+l*64,
        Bh, Ch, dstP, srcP, t16, buckets);
    k_agg<<<dim3(NNODE/4), blk, 0, stream>>>(e, Vh, srcP, row_ptr,
        invc, Uh, buckets);
    k_redstats<<<dim3(1), blk, 0, stream>>>(buckets, stats);
    k_node_finB<<<dim3(NH/256), blk, 0, stream>>>(Uh, h, stats, hg+l*64, hb+l*64);
    k_ebn<<<dim3(NE/8/256), blk, 0, stream>>>(t16, stats, eg+l*64, eb+l*64, e);
  }
  k_mlp<<<dim3(NEDGE/64), blk, 0, stream>>>(e, eidP, f1w, f1b, f2w, f2b,
                                            f3w, f3b, (float*)d_out);
}